// Round 5
// baseline (2499.205 us; speedup 1.0000x reference)
//
#include <hip/hip_runtime.h>
#include <stdint.h>

#pragma clang fp contract(off)

#define BATCH 16
#define CCH   512
#define NLEN  1024
#define NH    8
#define DH    64

// ================= numpy-pairwise emulation (f32, no contraction) =================
__device__ float pw128(const float* __restrict__ x) {
    float r0=x[0],r1=x[1],r2=x[2],r3=x[3],r4=x[4],r5=x[5],r6=x[6],r7=x[7];
    for (int i = 8; i < 128; i += 8) {
        r0 += x[i+0]; r1 += x[i+1]; r2 += x[i+2]; r3 += x[i+3];
        r4 += x[i+4]; r5 += x[i+5]; r6 += x[i+6]; r7 += x[i+7];
    }
    return ((r0+r1)+(r2+r3))+((r4+r5)+(r6+r7));
}
__device__ float pw128_sqdev(const float* __restrict__ x, float m) {
    float r0,r1,r2,r3,r4,r5,r6,r7;
    {
        float d;
        d = x[0]-m; r0 = d*d;  d = x[1]-m; r1 = d*d;
        d = x[2]-m; r2 = d*d;  d = x[3]-m; r3 = d*d;
        d = x[4]-m; r4 = d*d;  d = x[5]-m; r5 = d*d;
        d = x[6]-m; r6 = d*d;  d = x[7]-m; r7 = d*d;
    }
    for (int i = 8; i < 128; i += 8) {
        float d;
        d = x[i+0]-m; r0 += d*d;  d = x[i+1]-m; r1 += d*d;
        d = x[i+2]-m; r2 += d*d;  d = x[i+3]-m; r3 += d*d;
        d = x[i+4]-m; r4 += d*d;  d = x[i+5]-m; r5 += d*d;
        d = x[i+6]-m; r6 += d*d;  d = x[i+7]-m; r7 += d*d;
    }
    return ((r0+r1)+(r2+r3))+((r4+r5)+(r6+r7));
}

// BN stats, numpy semantics (bit-exact): pairwise mean, two-pass var, CR f32 rsqrt.
__global__ __launch_bounds__(64) void bn_stats_np_k(const float* __restrict__ Y, int O,
                                                    float2* __restrict__ st)
{
    const int o = blockIdx.x;
    const int t = threadIdx.x;
    const int bi = t >> 2, q = t & 3;
    __shared__ float part[64];
    __shared__ float msh;
    const float* p = Y + ((size_t)bi * O + o) * NLEN + q * 256;
    {
        float s0 = pw128(p), s1 = pw128(p + 128);
        part[t] = s0 + s1;
    }
    __syncthreads();
    if (t == 0) {
        float s = 0.0f;
        for (int b = 0; b < 16; ++b) {
            const float* pp = &part[b * 4];
            float v = (pp[0] + pp[1]) + (pp[2] + pp[3]);
            s = (b == 0) ? v : (s + v);
        }
        msh = s / 16384.0f;
    }
    __syncthreads();
    const float m = msh;
    {
        float s0 = pw128_sqdev(p, m), s1 = pw128_sqdev(p + 128, m);
        part[t] = s0 + s1;
    }
    __syncthreads();
    if (t == 0) {
        float s = 0.0f;
        for (int b = 0; b < 16; ++b) {
            const float* pp = &part[b * 4];
            float v = (pp[0] + pp[1]) + (pp[2] + pp[3]);
            s = (b == 0) ? v : (s + v);
        }
        float var = s / 16384.0f;
        float ve  = var + 1e-5f;
        float sq  = (float)sqrt((double)ve);    // correctly-rounded f32 sqrt
        float r   = (float)(1.0 / (double)sq);  // correctly-rounded f32 reciprocal
        st[o] = make_float2(m, r);
    }
}

// spike of bn output, f32 reference op order
__device__ inline bool spike_f32(float y, float2 s, float g, float b) {
    float t1 = y - s.x;
    float t2 = t1 * s.y;
    float t3 = t2 * g;
    float t4 = t3 + b;
    float u  = t4 / 2.0f - 1.0f;
    return u >= 0.0f;
}

// ===== Dense GEMM (r11): 128x128 tile, 128 thr, 16x8/thread, BK=16 dbuf, both ops in LDS =====
// r9 was LDS-BW bound: 8x8 tile = 1.0 B/FMA -> 128 B/cy/CU demand vs ~85-128 capacity.
// 16x8 tile = 0.75 B/FMA -> 96 B/cy demand; A-reads are 4-address broadcasts (cheap).
// __launch_bounds__(128,2): pins allocator at <=256 VGPR (r10's heuristic chose 64 and died);
// 4 blocks/CU x 33.8 KB LDS = 135 KB. FMA chain per output unchanged -> bit-exact.
// MODE 0: fused qkv, W selected by blockIdx.y (0-3:Wq 4-7:Wk 8-11:Wv), X = Xf
// MODE 2: single W, X = f32(Xf + Xs8)
template<int MODE>
__global__ __launch_bounds__(128, 2) void gemm_k(
    const float* __restrict__ Wq, const float* __restrict__ Wk, const float* __restrict__ Wv,
    const float* __restrict__ Xf, const uint8_t* __restrict__ Xs8,
    const float* __restrict__ bias, float* __restrict__ Y,
    int O, int Cin, int N)
{
    __shared__ float Ws[2][16][132];
    __shared__ float Xs[2][16][132];
    const int b = blockIdx.z;
    const size_t xbase = (size_t)b * Cin * N;
    float* Yb = Y + (size_t)b * O * N;
    const int oy  = blockIdx.y;
    const int o0y = oy * 128;                 // output channel base
    const float* W;
    int o0w;                                  // row base within W
    if (MODE == 0) {
        W   = (oy < 4) ? Wq : (oy < 8) ? Wk : Wv;
        o0w = (oy & 3) * 128;
    } else {
        W   = Wq;
        o0w = o0y;
    }
    const int n0 = blockIdx.x * 128;
    const int t  = threadIdx.x;               // 0..127
    const int tx = t & 15;                    // n-group
    const int ty = t >> 4;                    // 0..7 o-subgroup

    const int xk = t >> 3;                    // k-row 0..15
    const int xc = (t & 7) << 4;              // n-offset 0,16,...,112

    float acc[16][8];
#pragma unroll
    for (int i = 0; i < 16; ++i)
#pragma unroll
        for (int j = 0; j < 8; ++j) acc[i][j] = 0.0f;

    float4 wA[4];
    float  xr[16];

    auto loadG = [&](int k0) {
        const float* wp = W + (size_t)(o0w + t) * Cin + k0;
#pragma unroll
        for (int j = 0; j < 4; ++j)
            wA[j] = *reinterpret_cast<const float4*>(wp + 4 * j);
        size_t off = xbase + (size_t)(k0 + xk) * N + n0 + xc;
#pragma unroll
        for (int j = 0; j < 4; ++j) {
            float4 v = *reinterpret_cast<const float4*>(Xf + off + 4 * j);
            if (MODE == 0) {
                xr[4*j+0]=v.x; xr[4*j+1]=v.y; xr[4*j+2]=v.z; xr[4*j+3]=v.w;
            } else {
                uchar4 u = *reinterpret_cast<const uchar4*>(Xs8 + off + 4 * j);
                xr[4*j+0]=v.x+(float)u.x; xr[4*j+1]=v.y+(float)u.y;
                xr[4*j+2]=v.z+(float)u.z; xr[4*j+3]=v.w+(float)u.w;
            }
        }
    };
    auto stage = [&](int buf) {
        // Ws[k][o]: lane o-rows consecutive -> 2 lanes/bank (free)
#pragma unroll
        for (int j = 0; j < 4; ++j) {
            Ws[buf][4*j+0][t]=wA[j].x; Ws[buf][4*j+1][t]=wA[j].y;
            Ws[buf][4*j+2][t]=wA[j].z; Ws[buf][4*j+3][t]=wA[j].w;
        }
#pragma unroll
        for (int j = 0; j < 4; ++j)
            *reinterpret_cast<float4*>(&Xs[buf][xk][xc + 4*j]) =
                make_float4(xr[4*j+0], xr[4*j+1], xr[4*j+2], xr[4*j+3]);
    };

    loadG(0);
    stage(0);
    __syncthreads();
    int cur = 0;
    for (int k0 = 0;;) {
        const int kn = k0 + 16;
        const bool more = kn < Cin;
        if (more) loadG(kn);            // issue next-tile global loads early
#pragma unroll
        for (int kk = 0; kk < 16; ++kk) {
            float4 a0 = *reinterpret_cast<const float4*>(&Ws[cur][kk][ty * 4]);
            float4 a1 = *reinterpret_cast<const float4*>(&Ws[cur][kk][32 + ty * 4]);
            float4 a2 = *reinterpret_cast<const float4*>(&Ws[cur][kk][64 + ty * 4]);
            float4 a3 = *reinterpret_cast<const float4*>(&Ws[cur][kk][96 + ty * 4]);
            float4 b0 = *reinterpret_cast<const float4*>(&Xs[cur][kk][tx * 4]);
            float4 b1 = *reinterpret_cast<const float4*>(&Xs[cur][kk][64 + tx * 4]);
            float av[16] = {a0.x,a0.y,a0.z,a0.w, a1.x,a1.y,a1.z,a1.w,
                            a2.x,a2.y,a2.z,a2.w, a3.x,a3.y,a3.z,a3.w};
            float bv[8]  = {b0.x,b0.y,b0.z,b0.w, b1.x,b1.y,b1.z,b1.w};
#pragma unroll
            for (int i = 0; i < 16; ++i)
#pragma unroll
                for (int j = 0; j < 8; ++j)
                    acc[i][j] = fmaf(av[i], bv[j], acc[i][j]);
        }
        if (!more) break;
        stage(cur ^ 1);
        __syncthreads();                // single barrier per K-step
        cur ^= 1;
        k0 = kn;
    }
#pragma unroll
    for (int q = 0; q < 4; ++q)
#pragma unroll
        for (int i = 0; i < 4; ++i) {
            const int r = q * 4 + i;
            const int o = o0y + q * 32 + ty * 4 + i;
            const float bb = bias ? bias[o - o0y + (MODE == 0 ? 0 : 0)] : 0.0f;
            // NOTE: bias pointer is pre-offset per launch; index within this gemm's O range
            float* yp = Yb + (size_t)o * N + n0;
            float4 r0, r1;
            r0.x = acc[r][0] + bb; r0.y = acc[r][1] + bb;
            r0.z = acc[r][2] + bb; r0.w = acc[r][3] + bb;
            r1.x = acc[r][4] + bb; r1.y = acc[r][5] + bb;
            r1.z = acc[r][6] + bb; r1.w = acc[r][7] + bb;
            *reinterpret_cast<float4*>(yp + tx * 4)      = r0;
            *reinterpret_cast<float4*>(yp + 64 + tx * 4) = r1;
        }
}

// ====== W transpose: Wt[k][o_off+o] = W[o][k] (bit-exact copy), column-offset variant ======
__global__ __launch_bounds__(256) void wt_k(const float* __restrict__ W, float* __restrict__ Wt,
                                            int O, int Cin, int o_off, int Otot)
{
    __shared__ float tile[32][33];
    const int k0 = blockIdx.x * 32, o0 = blockIdx.y * 32;
    const int tx = threadIdx.x & 31, ty = threadIdx.x >> 5;  // ty 0..7
#pragma unroll
    for (int j = 0; j < 4; ++j)
        tile[ty + 8*j][tx] = W[(size_t)(o0 + ty + 8*j) * Cin + k0 + tx];
    __syncthreads();
#pragma unroll
    for (int j = 0; j < 4; ++j)
        Wt[(size_t)(k0 + ty + 8*j) * Otot + o_off + o0 + tx] = tile[tx][ty + 8*j];
}

// ================= bit-pack spike columns: bits[b][n][k/64] (bit k%64) =================
__global__ __launch_bounds__(256) void col_bits_k(const uint8_t* __restrict__ S,
                                                  unsigned long long* __restrict__ bits, int Cin)
{
    // grid: (N/64, Cin/64, B)
    const int n0 = blockIdx.x * 64, kw = blockIdx.y, b = blockIdx.z;
    __shared__ uint8_t tile[64][64];   // [k][n], rows 64 B -> 16B-aligned
    const int t = threadIdx.x;
    const int r = t >> 2, cg = (t & 3) * 16;
    const uint8_t* src = S + ((size_t)b * Cin + kw * 64 + r) * NLEN + n0 + cg;
    *reinterpret_cast<uint4*>(&tile[r][cg]) = *reinterpret_cast<const uint4*>(src);
    __syncthreads();
    if (t < 64) {
        unsigned long long m = 0;
#pragma unroll
        for (int rr = 0; rr < 64; ++rr)
            m |= ((unsigned long long)(tile[rr][t] != 0)) << rr;
        bits[((size_t)b * NLEN + n0 + t) * (Cin >> 6) + kw] = m;
    }
}

// ================= sparse GEMM (binary X): one wave per (b,n) column, O=512 =================
__global__ __launch_bounds__(256) void sparse_gemm_k(
    const float* __restrict__ Wt, const unsigned long long* __restrict__ bits,
    const float* __restrict__ bias, float* __restrict__ Y, int Cin)
{
    const int wid  = (blockIdx.x << 2) + (threadIdx.x >> 6);
    const int lane = threadIdx.x & 63;
    const int b = wid >> 10, n = wid & 1023;
    const int W64 = Cin >> 6;
    float acc[8];
#pragma unroll
    for (int i = 0; i < 8; ++i) acc[i] = 0.0f;
    const unsigned long long* bp = bits + ((size_t)b * NLEN + n) * W64;
    for (int w = 0; w < W64; ++w) {
        unsigned long long m = bp[w];
        while (m) {
            const int bit = __builtin_ctzll(m);
            m &= m - 1;
            const int k = (w << 6) + bit;
            const float* wr = Wt + ((size_t)k << 9) + lane * 8;  // O=512
            float4 w0 = *reinterpret_cast<const float4*>(wr);
            float4 w1 = *reinterpret_cast<const float4*>(wr + 4);
            acc[0] += w0.x; acc[1] += w0.y; acc[2] += w0.z; acc[3] += w0.w;
            acc[4] += w1.x; acc[5] += w1.y; acc[6] += w1.z; acc[7] += w1.w;
        }
    }
    const float* bq = bias + lane * 8;
    float4 b0 = *reinterpret_cast<const float4*>(bq);
    float4 b1 = *reinterpret_cast<const float4*>(bq + 4);
    float bi[8] = {b0.x, b0.y, b0.z, b0.w, b1.x, b1.y, b1.z, b1.w};
    float* yp = Y + ((size_t)b * 512 + lane * 8) * NLEN + n;
#pragma unroll
    for (int i = 0; i < 8; ++i)
        yp[(size_t)i * NLEN] = acc[i] + bi[i];
}

// ======== fused qkv spike + transpose to [B,H,N,D] u8 (selects tensor by blockIdx.y) ========
__global__ __launch_bounds__(256) void spike_pack_qkv_k(
    const float* __restrict__ Y, const float2* __restrict__ st,
    const float* __restrict__ gq, const float* __restrict__ gk, const float* __restrict__ gv,
    const float* __restrict__ bq, const float* __restrict__ bk, const float* __restrict__ bv,
    uint8_t* __restrict__ oq, uint8_t* __restrict__ ok, uint8_t* __restrict__ ov)
{
    const int nt = blockIdx.x, hs = blockIdx.y, b = blockIdx.z;  // hs 0..23
    const int tensor = hs >> 3, h = hs & 7;
    const float* g  = (tensor == 0) ? gq : (tensor == 1) ? gk : gv;
    const float* be = (tensor == 0) ? bq : (tensor == 1) ? bk : bv;
    uint8_t* outp   = (tensor == 0) ? oq : (tensor == 1) ? ok : ov;
    __shared__ uint8_t tile[64][68];
    const int t = threadIdx.x;
    {
        const int i = t & 63, dq = t >> 6;
#pragma unroll
        for (int p = 0; p < 16; ++p) {
            int d  = dq * 16 + p;
            int cf = hs * 64 + d;            // fused channel 0..1535
            int cl = h * 64 + d;             // per-tensor channel 0..511
            float y = Y[((size_t)b * 1536 + cf) * NLEN + nt * 64 + i];
            tile[d][i] = spike_f32(y, st[cf], g[cl], be[cl]) ? 1 : 0;
        }
    }
    __syncthreads();
    {
        const int d = t & 63, iq = t >> 6;
#pragma unroll
        for (int p = 0; p < 16; ++p) {
            int i = iq * 16 + p;
            outp[((size_t)(b * NH + h) * NLEN + nt * 64 + i) * DH + d] = tile[d][i];
        }
    }
}

// ====== M partial = K^T V over a 128-position chunk (integers exact in f32) ======
// grid (BH=128, 8 chunks): full GPU instead of 128 blocks.
__global__ __launch_bounds__(256) void ktv_part_k(const uint8_t* __restrict__ Kb,
                                                  const uint8_t* __restrict__ Vb,
                                                  float* __restrict__ Mp)
{
    const int bh = blockIdx.x, ch = blockIdx.y;
    const uint8_t* kp = Kb + (size_t)bh * NLEN * DH;
    const uint8_t* vp = Vb + (size_t)bh * NLEN * DH;
    __shared__ float ks[64][68];
    __shared__ float vs[64][68];
    const int t = threadIdx.x;
    const int d2 = t & 63, g4 = t >> 6;
    float acc[16];
#pragma unroll
    for (int j = 0; j < 16; ++j) acc[j] = 0.f;

    for (int nc = ch * 128; nc < ch * 128 + 128; nc += 64) {
#pragma unroll
        for (int p = 0; p < 16; ++p) {
            int idx = t + p * 256;
            int r = idx >> 6, d = idx & 63;
            ks[r][d] = (float)kp[(size_t)(nc + r) * DH + d];
            vs[r][d] = (float)vp[(size_t)(nc + r) * DH + d];
        }
        __syncthreads();
        for (int n = 0; n < 64; ++n) {
            float vv = vs[n][d2];
#pragma unroll
            for (int j = 0; j < 16; ++j)
                acc[j] += ks[n][g4 * 16 + j] * vv;
        }
        __syncthreads();
    }
#pragma unroll
    for (int j = 0; j < 16; ++j)
        Mp[((size_t)ch * 128 + bh) * 4096 + (size_t)(g4 * 16 + j) * 64 + d2] = acc[j];
}

// ====== M = sum of 8 integer partials (exact in f32, order-free) ======
__global__ __launch_bounds__(256) void ktv_reduce_k(const float* __restrict__ Mp,
                                                    float* __restrict__ M)
{
    const int bh = blockIdx.x;
    const int t = threadIdx.x;
#pragma unroll
    for (int j = 0; j < 16; j += 4) {
        const int idx = t * 16 + j;
        float4 s = *reinterpret_cast<const float4*>(&Mp[(size_t)bh * 4096 + idx]);
#pragma unroll
        for (int c = 1; c < 8; ++c) {
            float4 v = *reinterpret_cast<const float4*>(&Mp[((size_t)c * 128 + bh) * 4096 + idx]);
            s.x += v.x; s.y += v.y; s.z += v.z; s.w += v.w;
        }
        *reinterpret_cast<float4*>(&M[(size_t)bh * 4096 + idx]) = s;
    }
}

// ================= attn = Q @ M, integer spike attn>=8, write [B,C,N] u8 =================
__global__ __launch_bounds__(256) void attn_spike_k(const uint8_t* __restrict__ Qb, const float* __restrict__ M,
                                                    uint8_t* __restrict__ A)
{
    const int nt = blockIdx.x, h = blockIdx.y, b = blockIdx.z;
    const int bh = b * NH + h;
    __shared__ float Ms[64][68];
    __shared__ float qs[64][65];
    const int t = threadIdx.x;
#pragma unroll
    for (int p = 0; p < 16; ++p) {
        int idx = t + p * 256;
        int r = idx >> 6, c = idx & 63;
        Ms[r][c] = M[(size_t)bh * 4096 + idx];
        qs[c][r] = (float)Qb[((size_t)bh * NLEN + nt * 64 + r) * DH + c];
    }
    __syncthreads();
    const int n = t & 63, dg = t >> 6;
    float acc[16];
#pragma unroll
    for (int j = 0; j < 16; ++j) acc[j] = 0.f;
    for (int d1 = 0; d1 < 64; ++d1) {
        float qv = qs[d1][n];
#pragma unroll
        for (int j = 0; j < 16; ++j)
            acc[j] += qv * Ms[d1][dg * 16 + j];
    }
#pragma unroll
    for (int j = 0; j < 16; ++j) {
        int d = dg * 16 + j;
        A[((size_t)b * CCH + h * 64 + d) * NLEN + nt * 64 + n] = (acc[j] >= 8.0f) ? 1 : 0;
    }
}

// ================= spike -> u8 store at channel offset =================
__global__ __launch_bounds__(256) void spike_store_k(
    const float* __restrict__ Y, const float2* __restrict__ st,
    const float* __restrict__ g, const float* __restrict__ bet,
    uint8_t* __restrict__ H, int Oc, int o_off, int Otot)
{
    size_t i4 = (size_t)blockIdx.x * 256 + threadIdx.x;
    size_t total = (size_t)BATCH * Oc * (NLEN / 4);
    if (i4 >= total) return;
    int n4 = (int)(i4 & 255);
    int o  = (int)((i4 >> 8) % Oc);
    int b  = (int)(i4 / ((size_t)256 * Oc));
    float4 y = reinterpret_cast<const float4*>(Y)[i4];
    float2 s = st[o];
    float gg = g[o], bb = bet[o];
    uchar4 r;
    r.x = spike_f32(y.x, s, gg, bb) ? 1 : 0;
    r.y = spike_f32(y.y, s, gg, bb) ? 1 : 0;
    r.z = spike_f32(y.z, s, gg, bb) ? 1 : 0;
    r.w = spike_f32(y.w, s, gg, bb) ? 1 : 0;
    *reinterpret_cast<uchar4*>(H + ((size_t)(b * Otot + o_off + o)) * NLEN + n4 * 4) = r;
}

// ================= out = (x + ares) + spike(bn(Y)) in np f32 order =================
__global__ __launch_bounds__(256) void final_k(
    const float* __restrict__ Y, const float2* __restrict__ st,
    const float* __restrict__ g, const float* __restrict__ bet,
    const float* __restrict__ x, const uint8_t* __restrict__ ares,
    float* __restrict__ Out)
{
    size_t i4 = (size_t)blockIdx.x * 256 + threadIdx.x;
    size_t total = (size_t)BATCH * CCH * (NLEN / 4);
    if (i4 >= total) return;
    int o = (int)((i4 >> 8) % CCH);
    float4 y  = reinterpret_cast<const float4*>(Y)[i4];
    float4 xv = reinterpret_cast<const float4*>(x)[i4];
    uchar4 av = reinterpret_cast<const uchar4*>(ares)[i4];
    float2 s = st[o];
    float gg = g[o], bb = bet[o];
    float4 r;
    {
        float x1;
        x1 = xv.x + (float)av.x; r.x = x1 + (spike_f32(y.x, s, gg, bb) ? 1.0f : 0.0f);
        x1 = xv.y + (float)av.y; r.y = x1 + (spike_f32(y.y, s, gg, bb) ? 1.0f : 0.0f);
        x1 = xv.z + (float)av.z; r.z = x1 + (spike_f32(y.z, s, gg, bb) ? 1.0f : 0.0f);
        x1 = xv.w + (float)av.w; r.w = x1 + (spike_f32(y.w, s, gg, bb) ? 1.0f : 0.0f);
    }
    reinterpret_cast<float4*>(Out)[i4] = r;
}

extern "C" void kernel_launch(void* const* d_in, const int* in_sizes, int n_in,
                              void* d_out, int out_size, void* d_ws, size_t ws_size,
                              hipStream_t stream)
{
    const float* x         = (const float*)d_in[0];
    const float* q_w       = (const float*)d_in[1];
    const float* q_g       = (const float*)d_in[2];
    const float* q_b       = (const float*)d_in[3];
    const float* k_w       = (const float*)d_in[4];
    const float* k_g       = (const float*)d_in[5];
    const float* k_b       = (const float*)d_in[6];
    const float* v_w       = (const float*)d_in[7];
    const float* v_g       = (const float*)d_in[8];
    const float* v_b       = (const float*)d_in[9];
    const float* proj_w    = (const float*)d_in[10];
    const float* proj_bias = (const float*)d_in[11];
    const float* proj_g    = (const float*)d_in[12];
    const float* proj_b    = (const float*)d_in[13];
    const float* fc1_w     = (const float*)d_in[14];
    const float* fc1_bias  = (const float*)d_in[15];
    const float* fc1_g     = (const float*)d_in[16];
    const float* fc1_b     = (const float*)d_in[17];
    const float* fc2_w     = (const float*)d_in[18];
    const float* fc2_bias  = (const float*)d_in[19];
    const float* fc2_g     = (const float*)d_in[20];
    const float* fc2_b     = (const float*)d_in[21];
    float* out = (float*)d_out;

    char* ws = (char*)d_ws;
    const size_t MiB = 1ull << 20;
    if (ws_size < 124 * MiB) return;

    // ---- layout (124 MiB), phase-checked lifetimes ----
    // Phase qkv : Yq 0-96 | qb 96-104 | kb 104-112 | vb 112-120 | stats 123+
    // Phase attn: Mpart 16-32 (Yq dead) | Mbuf 120-122 | ab 0-8
    // Phase proj: Wt 104-108, bits 108-112 (kb/vb dead) | Af 0-64 | ares 64-72
    // Phase fc1 : Af 0-64 | hb 72-104 (qb dead)
    // Phase fc2 : Wt 104-108, bits 108-112 | Af 0-64 | final reads ares 64-72
    float*    Yq    = (float*)(ws);                  // 96 MiB fused qkv out
    float*    Af    = (float*)(ws);                  // 64 MiB GEMM out (later phases)
    uint8_t*  ab    = (uint8_t*)(ws);                //  8 MiB attention spikes
    float*    Mpart = (float*)(ws + 16 * MiB);       // 16 MiB ktv partials (attn phase)
    uint8_t*  ares  = (uint8_t*)(ws + 64 * MiB);     //  8 MiB proj spikes, live to end
    uint8_t*  hb    = (uint8_t*)(ws + 72 * MiB);     // 32 MiB fc1 spikes (72..104)
    uint8_t*  qb    = (uint8_t*)(ws + 96 * MiB);     //  8 MiB [B,H,N,D]
    uint8_t*  kb    = (uint8_t*)(ws + 104 * MiB);    //  8 MiB
    uint8_t*  vb    = (uint8_t*)(ws + 112 * MiB);    //  8 MiB
    float*    Wt    = (float*)(ws + 104 * MiB);      //  4 MiB (sparse Wt; kb dead by proj)
    unsigned long long* bits = (unsigned long long*)(ws + 108 * MiB);  // 4 MiB
    float*    Mbuf  = (float*)(ws + 120 * MiB);      //  2 MiB (attn phase)
    float2*   stats = (float2*)(ws + 123 * MiB);     // 12 KiB (1536 ch max)

    dim3 thr256(256), thr128(128);

    // --- fused q|k|v dense GEMM: W selected per-block, no weight copies ---
    gemm_k<0><<<dim3(8, 12, 16), thr128, 0, stream>>>(q_w, k_w, v_w, x, nullptr, nullptr, Yq,
                                                      1536, 512, 1024);
    bn_stats_np_k<<<dim3(1536), dim3(64), 0, stream>>>(Yq, 1536, stats);
    spike_pack_qkv_k<<<dim3(16, 24, 16), thr256, 0, stream>>>(Yq, stats, q_g, k_g, v_g,
                                                              q_b, k_b, v_b, qb, kb, vb);

    // --- attention (exact integers; ktv split 8x for occupancy) ---
    ktv_part_k<<<dim3(128, 8), thr256, 0, stream>>>(kb, vb, Mpart);
    ktv_reduce_k<<<dim3(128), thr256, 0, stream>>>(Mpart, Mbuf);
    attn_spike_k<<<dim3(16, 8, 16), thr256, 0, stream>>>(qb, Mbuf, ab);

    // --- proj (sparse binary-input GEMM) ---
    wt_k<<<dim3(16, 16), thr256, 0, stream>>>(proj_w, Wt, 512, 512, 0, 512);
    col_bits_k<<<dim3(16, 8, 16), thr256, 0, stream>>>(ab, bits, 512);
    sparse_gemm_k<<<dim3(4096), thr256, 0, stream>>>(Wt, bits, proj_bias, Af, 512);
    bn_stats_np_k<<<dim3(512), dim3(64), 0, stream>>>(Af, 512, stats);
    spike_store_k<<<dim3(8192), thr256, 0, stream>>>(Af, stats, proj_g, proj_b, ares, 512, 0, 512);

    // --- fc1 on x1 = f32(x + ares), dense, 2 chunks of 1024 out-ch ---
    for (int ch = 0; ch < 2; ++ch) {
        const float* Wc = fc1_w + (size_t)ch * 1024 * 512;
        gemm_k<2><<<dim3(8, 8, 16), thr128, 0, stream>>>(Wc, Wc, Wc, x, ares,
                                                         fc1_bias + ch * 1024, Af,
                                                         1024, 512, 1024);
        bn_stats_np_k<<<dim3(1024), dim3(64), 0, stream>>>(Af, 1024, stats);
        spike_store_k<<<dim3(16384), thr256, 0, stream>>>(Af, stats, fc1_g + ch * 1024, fc1_b + ch * 1024,
                                                          hb, 1024, ch * 1024, 2048);
    }

    // --- fc2 (sparse binary-input GEMM) + final residual ---
    wt_k<<<dim3(64, 16), thr256, 0, stream>>>(fc2_w, Wt, 512, 2048, 0, 512);
    col_bits_k<<<dim3(16, 32, 16), thr256, 0, stream>>>(hb, bits, 2048);
    sparse_gemm_k<<<dim3(4096), thr256, 0, stream>>>(Wt, bits, fc2_bias, Af, 2048);
    bn_stats_np_k<<<dim3(512), dim3(64), 0, stream>>>(Af, 512, stats);
    final_k<<<dim3(8192), thr256, 0, stream>>>(Af, stats, fc2_g, fc2_b, x, ares, out);
}

// Round 6
// 2136.801 us; speedup vs baseline: 1.1696x; 1.1696x over previous
//
#include <hip/hip_runtime.h>
#include <stdint.h>

#pragma clang fp contract(off)

#define BATCH 16
#define CCH   512
#define NLEN  1024
#define NH    8
#define DH    64

// ================= numpy-pairwise emulation (f32, no contraction) =================
__device__ float pw128(const float* __restrict__ x) {
    float r0=x[0],r1=x[1],r2=x[2],r3=x[3],r4=x[4],r5=x[5],r6=x[6],r7=x[7];
    for (int i = 8; i < 128; i += 8) {
        r0 += x[i+0]; r1 += x[i+1]; r2 += x[i+2]; r3 += x[i+3];
        r4 += x[i+4]; r5 += x[i+5]; r6 += x[i+6]; r7 += x[i+7];
    }
    return ((r0+r1)+(r2+r3))+((r4+r5)+(r6+r7));
}
__device__ float pw128_sqdev(const float* __restrict__ x, float m) {
    float r0,r1,r2,r3,r4,r5,r6,r7;
    {
        float d;
        d = x[0]-m; r0 = d*d;  d = x[1]-m; r1 = d*d;
        d = x[2]-m; r2 = d*d;  d = x[3]-m; r3 = d*d;
        d = x[4]-m; r4 = d*d;  d = x[5]-m; r5 = d*d;
        d = x[6]-m; r6 = d*d;  d = x[7]-m; r7 = d*d;
    }
    for (int i = 8; i < 128; i += 8) {
        float d;
        d = x[i+0]-m; r0 += d*d;  d = x[i+1]-m; r1 += d*d;
        d = x[i+2]-m; r2 += d*d;  d = x[i+3]-m; r3 += d*d;
        d = x[i+4]-m; r4 += d*d;  d = x[i+5]-m; r5 += d*d;
        d = x[i+6]-m; r6 += d*d;  d = x[i+7]-m; r7 += d*d;
    }
    return ((r0+r1)+(r2+r3))+((r4+r5)+(r6+r7));
}

// BN stats, numpy semantics (bit-exact): pairwise mean, two-pass var, CR f32 rsqrt.
__global__ __launch_bounds__(64) void bn_stats_np_k(const float* __restrict__ Y, int O,
                                                    float2* __restrict__ st)
{
    const int o = blockIdx.x;
    const int t = threadIdx.x;
    const int bi = t >> 2, q = t & 3;
    __shared__ float part[64];
    __shared__ float msh;
    const float* p = Y + ((size_t)bi * O + o) * NLEN + q * 256;
    {
        float s0 = pw128(p), s1 = pw128(p + 128);
        part[t] = s0 + s1;
    }
    __syncthreads();
    if (t == 0) {
        float s = 0.0f;
        for (int b = 0; b < 16; ++b) {
            const float* pp = &part[b * 4];
            float v = (pp[0] + pp[1]) + (pp[2] + pp[3]);
            s = (b == 0) ? v : (s + v);
        }
        msh = s / 16384.0f;
    }
    __syncthreads();
    const float m = msh;
    {
        float s0 = pw128_sqdev(p, m), s1 = pw128_sqdev(p + 128, m);
        part[t] = s0 + s1;
    }
    __syncthreads();
    if (t == 0) {
        float s = 0.0f;
        for (int b = 0; b < 16; ++b) {
            const float* pp = &part[b * 4];
            float v = (pp[0] + pp[1]) + (pp[2] + pp[3]);
            s = (b == 0) ? v : (s + v);
        }
        float var = s / 16384.0f;
        float ve  = var + 1e-5f;
        float sq  = (float)sqrt((double)ve);    // correctly-rounded f32 sqrt
        float r   = (float)(1.0 / (double)sq);  // correctly-rounded f32 reciprocal
        st[o] = make_float2(m, r);
    }
}

// spike of bn output, f32 reference op order
__device__ inline bool spike_f32(float y, float2 s, float g, float b) {
    float t1 = y - s.x;
    float t2 = t1 * s.y;
    float t3 = t2 * g;
    float t4 = t3 + b;
    float u  = t4 / 2.0f - 1.0f;
    return u >= 0.0f;
}

// ===== Dense GEMM (r12): 128x128 tile, 256 thr (4 waves), SGPR-broadcast A =====
// r9 was LDS-issue bound (4 ds_read_b128/kk/wave, ratio 1.5). New layout: wave owns
// 32 o-rows x 128 n; lane owns 2 n-cols -> acc[32][2] = 64 VGPR (allocator-safe size;
// >64 acc regs spilled in r7/r10/r11). Per kk the 32 A values are wave-uniform
// (addr from readfirstlane'd wid) -> backend emits s_load to SGPRs on the scalar pipe:
// A costs no VALU/LDS/VGPR. LDS keeps only X: 1 ds_read_b64/kk/wave (ratio ~0.2).
// Bit-exactness: per output strict ascending-k sequential fmaf chain, bias added once.
// Wt is the bit-exact transposed weight Wt[k][o_base+o] built by wt_k.
// MODE 0: X = Xf (f32)   MODE 2: X = f32(Xf + Xs8)
template<int MODE>
__global__ __launch_bounds__(256) void gemm_k(
    const float* __restrict__ Wt, const float* __restrict__ Xf, const uint8_t* __restrict__ Xs8,
    const float* __restrict__ bias, float* __restrict__ Y,
    int O, int Cin, int N, int ldW)
{
    __shared__ float Xs[2][16][132];
    const int b = blockIdx.z;
    const size_t xbase = (size_t)b * Cin * N;
    float* Yb = Y + (size_t)b * O * N;
    const int o0 = blockIdx.y * 128;
    const int n0 = blockIdx.x * 128;
    const int t  = threadIdx.x;
    const int wid  = __builtin_amdgcn_readfirstlane(t >> 6);   // 0..3, wave-uniform
    const int lane = t & 63;

    const int xk = t >> 4;          // k-row 0..15
    const int xc = (t & 15) << 3;   // n-offset 0,8,...,120

    float acc[32][2];
#pragma unroll
    for (int r = 0; r < 32; ++r) { acc[r][0] = 0.0f; acc[r][1] = 0.0f; }

    float xr[8];

    auto loadGX = [&](int k0) {
        size_t off = xbase + (size_t)(k0 + xk) * N + n0 + xc;
        float4 v0 = *reinterpret_cast<const float4*>(Xf + off);
        float4 v1 = *reinterpret_cast<const float4*>(Xf + off + 4);
        if (MODE == 0) {
            xr[0]=v0.x; xr[1]=v0.y; xr[2]=v0.z; xr[3]=v0.w;
            xr[4]=v1.x; xr[5]=v1.y; xr[6]=v1.z; xr[7]=v1.w;
        } else {
            uchar4 u0 = *reinterpret_cast<const uchar4*>(Xs8 + off);
            uchar4 u1 = *reinterpret_cast<const uchar4*>(Xs8 + off + 4);
            xr[0]=v0.x+(float)u0.x; xr[1]=v0.y+(float)u0.y;
            xr[2]=v0.z+(float)u0.z; xr[3]=v0.w+(float)u0.w;
            xr[4]=v1.x+(float)u1.x; xr[5]=v1.y+(float)u1.y;
            xr[6]=v1.z+(float)u1.z; xr[7]=v1.w+(float)u1.w;
        }
    };
    auto stageX = [&](int buf) {
        *reinterpret_cast<float4*>(&Xs[buf][xk][xc])     = make_float4(xr[0],xr[1],xr[2],xr[3]);
        *reinterpret_cast<float4*>(&Xs[buf][xk][xc + 4]) = make_float4(xr[4],xr[5],xr[6],xr[7]);
    };

    const float* wcol = Wt + o0 + wid * 32;   // wave-uniform; + k*ldW per kk row

    loadGX(0);
    stageX(0);
    __syncthreads();
    int cur = 0;
    for (int k0 = 0;;) {
        const int kn = k0 + 16;
        const bool more = kn < Cin;
        if (more) loadGX(kn);            // issue next-tile X loads early
#pragma unroll
        for (int kk = 0; kk < 16; ++kk) {
            const float* ap = wcol + (size_t)(k0 + kk) * ldW;   // uniform -> s_load
            float2 bv = *reinterpret_cast<const float2*>(&Xs[cur][kk][lane * 2]);
#pragma unroll
            for (int r = 0; r < 32; ++r) {
                const float a = ap[r];
                acc[r][0] = fmaf(a, bv.x, acc[r][0]);
                acc[r][1] = fmaf(a, bv.y, acc[r][1]);
            }
        }
        if (!more) break;
        stageX(cur ^ 1);
        __syncthreads();                 // single barrier per K-step
        cur ^= 1;
        k0 = kn;
    }
#pragma unroll
    for (int r = 0; r < 32; ++r) {
        const int o = o0 + wid * 32 + r;
        const float bb = bias ? bias[o] : 0.0f;
        float2 v;
        v.x = acc[r][0] + bb;
        v.y = acc[r][1] + bb;
        *reinterpret_cast<float2*>(Yb + (size_t)o * N + n0 + lane * 2) = v;
    }
}

// ====== W transpose: Wt[k][o_off+o] = W[o][k] (bit-exact copy), column-offset variant ======
__global__ __launch_bounds__(256) void wt_k(const float* __restrict__ W, float* __restrict__ Wt,
                                            int O, int Cin, int o_off, int Otot)
{
    __shared__ float tile[32][33];
    const int k0 = blockIdx.x * 32, o0 = blockIdx.y * 32;
    const int tx = threadIdx.x & 31, ty = threadIdx.x >> 5;  // ty 0..7
#pragma unroll
    for (int j = 0; j < 4; ++j)
        tile[ty + 8*j][tx] = W[(size_t)(o0 + ty + 8*j) * Cin + k0 + tx];
    __syncthreads();
#pragma unroll
    for (int j = 0; j < 4; ++j)
        Wt[(size_t)(k0 + ty + 8*j) * Otot + o_off + o0 + tx] = tile[tx][ty + 8*j];
}

// ================= bit-pack spike columns: bits[b][n][k/64] (bit k%64) =================
__global__ __launch_bounds__(256) void col_bits_k(const uint8_t* __restrict__ S,
                                                  unsigned long long* __restrict__ bits, int Cin)
{
    // grid: (N/64, Cin/64, B)
    const int n0 = blockIdx.x * 64, kw = blockIdx.y, b = blockIdx.z;
    __shared__ uint8_t tile[64][64];   // [k][n], rows 64 B -> 16B-aligned
    const int t = threadIdx.x;
    const int r = t >> 2, cg = (t & 3) * 16;
    const uint8_t* src = S + ((size_t)b * Cin + kw * 64 + r) * NLEN + n0 + cg;
    *reinterpret_cast<uint4*>(&tile[r][cg]) = *reinterpret_cast<const uint4*>(src);
    __syncthreads();
    if (t < 64) {
        unsigned long long m = 0;
#pragma unroll
        for (int rr = 0; rr < 64; ++rr)
            m |= ((unsigned long long)(tile[rr][t] != 0)) << rr;
        bits[((size_t)b * NLEN + n0 + t) * (Cin >> 6) + kw] = m;
    }
}

// ================= sparse GEMM (binary X): one wave per (b,n) column, O=512 =================
__global__ __launch_bounds__(256) void sparse_gemm_k(
    const float* __restrict__ Wt, const unsigned long long* __restrict__ bits,
    const float* __restrict__ bias, float* __restrict__ Y, int Cin)
{
    const int wid  = (blockIdx.x << 2) + (threadIdx.x >> 6);
    const int lane = threadIdx.x & 63;
    const int b = wid >> 10, n = wid & 1023;
    const int W64 = Cin >> 6;
    float acc[8];
#pragma unroll
    for (int i = 0; i < 8; ++i) acc[i] = 0.0f;
    const unsigned long long* bp = bits + ((size_t)b * NLEN + n) * W64;
    for (int w = 0; w < W64; ++w) {
        unsigned long long m = bp[w];
        while (m) {
            const int bit = __builtin_ctzll(m);
            m &= m - 1;
            const int k = (w << 6) + bit;
            const float* wr = Wt + ((size_t)k << 9) + lane * 8;  // O=512
            float4 w0 = *reinterpret_cast<const float4*>(wr);
            float4 w1 = *reinterpret_cast<const float4*>(wr + 4);
            acc[0] += w0.x; acc[1] += w0.y; acc[2] += w0.z; acc[3] += w0.w;
            acc[4] += w1.x; acc[5] += w1.y; acc[6] += w1.z; acc[7] += w1.w;
        }
    }
    const float* bq = bias + lane * 8;
    float4 b0 = *reinterpret_cast<const float4*>(bq);
    float4 b1 = *reinterpret_cast<const float4*>(bq + 4);
    float bi[8] = {b0.x, b0.y, b0.z, b0.w, b1.x, b1.y, b1.z, b1.w};
    float* yp = Y + ((size_t)b * 512 + lane * 8) * NLEN + n;
#pragma unroll
    for (int i = 0; i < 8; ++i)
        yp[(size_t)i * NLEN] = acc[i] + bi[i];
}

// ======== fused qkv spike + transpose to [B,H,N,D] u8 (selects tensor by blockIdx.y) ========
__global__ __launch_bounds__(256) void spike_pack_qkv_k(
    const float* __restrict__ Y, const float2* __restrict__ st,
    const float* __restrict__ gq, const float* __restrict__ gk, const float* __restrict__ gv,
    const float* __restrict__ bq, const float* __restrict__ bk, const float* __restrict__ bv,
    uint8_t* __restrict__ oq, uint8_t* __restrict__ ok, uint8_t* __restrict__ ov)
{
    const int nt = blockIdx.x, hs = blockIdx.y, b = blockIdx.z;  // hs 0..23
    const int tensor = hs >> 3, h = hs & 7;
    const float* g  = (tensor == 0) ? gq : (tensor == 1) ? gk : gv;
    const float* be = (tensor == 0) ? bq : (tensor == 1) ? bk : bv;
    uint8_t* outp   = (tensor == 0) ? oq : (tensor == 1) ? ok : ov;
    __shared__ uint8_t tile[64][68];
    const int t = threadIdx.x;
    {
        const int i = t & 63, dq = t >> 6;
#pragma unroll
        for (int p = 0; p < 16; ++p) {
            int d  = dq * 16 + p;
            int cf = hs * 64 + d;            // fused channel 0..1535
            int cl = h * 64 + d;             // per-tensor channel 0..511
            float y = Y[((size_t)b * 1536 + cf) * NLEN + nt * 64 + i];
            tile[d][i] = spike_f32(y, st[cf], g[cl], be[cl]) ? 1 : 0;
        }
    }
    __syncthreads();
    {
        const int d = t & 63, iq = t >> 6;
#pragma unroll
        for (int p = 0; p < 16; ++p) {
            int i = iq * 16 + p;
            outp[((size_t)(b * NH + h) * NLEN + nt * 64 + i) * DH + d] = tile[d][i];
        }
    }
}

// ====== M partial = K^T V over a 128-position chunk (integers exact in f32) ======
__global__ __launch_bounds__(256) void ktv_part_k(const uint8_t* __restrict__ Kb,
                                                  const uint8_t* __restrict__ Vb,
                                                  float* __restrict__ Mp)
{
    const int bh = blockIdx.x, ch = blockIdx.y;
    const uint8_t* kp = Kb + (size_t)bh * NLEN * DH;
    const uint8_t* vp = Vb + (size_t)bh * NLEN * DH;
    __shared__ float ks[64][68];
    __shared__ float vs[64][68];
    const int t = threadIdx.x;
    const int d2 = t & 63, g4 = t >> 6;
    float acc[16];
#pragma unroll
    for (int j = 0; j < 16; ++j) acc[j] = 0.f;

    for (int nc = ch * 128; nc < ch * 128 + 128; nc += 64) {
#pragma unroll
        for (int p = 0; p < 16; ++p) {
            int idx = t + p * 256;
            int r = idx >> 6, d = idx & 63;
            ks[r][d] = (float)kp[(size_t)(nc + r) * DH + d];
            vs[r][d] = (float)vp[(size_t)(nc + r) * DH + d];
        }
        __syncthreads();
        for (int n = 0; n < 64; ++n) {
            float vv = vs[n][d2];
#pragma unroll
            for (int j = 0; j < 16; ++j)
                acc[j] += ks[n][g4 * 16 + j] * vv;
        }
        __syncthreads();
    }
#pragma unroll
    for (int j = 0; j < 16; ++j)
        Mp[((size_t)ch * 128 + bh) * 4096 + (size_t)(g4 * 16 + j) * 64 + d2] = acc[j];
}

// ====== M = sum of 8 integer partials (exact in f32, order-free) ======
__global__ __launch_bounds__(256) void ktv_reduce_k(const float* __restrict__ Mp,
                                                    float* __restrict__ M)
{
    const int bh = blockIdx.x;
    const int t = threadIdx.x;
#pragma unroll
    for (int j = 0; j < 16; j += 4) {
        const int idx = t * 16 + j;
        float4 s = *reinterpret_cast<const float4*>(&Mp[(size_t)bh * 4096 + idx]);
#pragma unroll
        for (int c = 1; c < 8; ++c) {
            float4 v = *reinterpret_cast<const float4*>(&Mp[((size_t)c * 128 + bh) * 4096 + idx]);
            s.x += v.x; s.y += v.y; s.z += v.z; s.w += v.w;
        }
        *reinterpret_cast<float4*>(&M[(size_t)bh * 4096 + idx]) = s;
    }
}

// ================= attn = Q @ M, integer spike attn>=8, write [B,C,N] u8 =================
__global__ __launch_bounds__(256) void attn_spike_k(const uint8_t* __restrict__ Qb, const float* __restrict__ M,
                                                    uint8_t* __restrict__ A)
{
    const int nt = blockIdx.x, h = blockIdx.y, b = blockIdx.z;
    const int bh = b * NH + h;
    __shared__ float Ms[64][68];
    __shared__ float qs[64][65];
    const int t = threadIdx.x;
#pragma unroll
    for (int p = 0; p < 16; ++p) {
        int idx = t + p * 256;
        int r = idx >> 6, c = idx & 63;
        Ms[r][c] = M[(size_t)bh * 4096 + idx];
        qs[c][r] = (float)Qb[((size_t)bh * NLEN + nt * 64 + r) * DH + c];
    }
    __syncthreads();
    const int n = t & 63, dg = t >> 6;
    float acc[16];
#pragma unroll
    for (int j = 0; j < 16; ++j) acc[j] = 0.f;
    for (int d1 = 0; d1 < 64; ++d1) {
        float qv = qs[d1][n];
#pragma unroll
        for (int j = 0; j < 16; ++j)
            acc[j] += qv * Ms[d1][dg * 16 + j];
    }
#pragma unroll
    for (int j = 0; j < 16; ++j) {
        int d = dg * 16 + j;
        A[((size_t)b * CCH + h * 64 + d) * NLEN + nt * 64 + n] = (acc[j] >= 8.0f) ? 1 : 0;
    }
}

// ================= spike -> u8 store at channel offset =================
__global__ __launch_bounds__(256) void spike_store_k(
    const float* __restrict__ Y, const float2* __restrict__ st,
    const float* __restrict__ g, const float* __restrict__ bet,
    uint8_t* __restrict__ H, int Oc, int o_off, int Otot)
{
    size_t i4 = (size_t)blockIdx.x * 256 + threadIdx.x;
    size_t total = (size_t)BATCH * Oc * (NLEN / 4);
    if (i4 >= total) return;
    int n4 = (int)(i4 & 255);
    int o  = (int)((i4 >> 8) % Oc);
    int b  = (int)(i4 / ((size_t)256 * Oc));
    float4 y = reinterpret_cast<const float4*>(Y)[i4];
    float2 s = st[o];
    float gg = g[o], bb = bet[o];
    uchar4 r;
    r.x = spike_f32(y.x, s, gg, bb) ? 1 : 0;
    r.y = spike_f32(y.y, s, gg, bb) ? 1 : 0;
    r.z = spike_f32(y.z, s, gg, bb) ? 1 : 0;
    r.w = spike_f32(y.w, s, gg, bb) ? 1 : 0;
    *reinterpret_cast<uchar4*>(H + ((size_t)(b * Otot + o_off + o)) * NLEN + n4 * 4) = r;
}

// ================= out = (x + ares) + spike(bn(Y)) in np f32 order =================
__global__ __launch_bounds__(256) void final_k(
    const float* __restrict__ Y, const float2* __restrict__ st,
    const float* __restrict__ g, const float* __restrict__ bet,
    const float* __restrict__ x, const uint8_t* __restrict__ ares,
    float* __restrict__ Out)
{
    size_t i4 = (size_t)blockIdx.x * 256 + threadIdx.x;
    size_t total = (size_t)BATCH * CCH * (NLEN / 4);
    if (i4 >= total) return;
    int o = (int)((i4 >> 8) % CCH);
    float4 y  = reinterpret_cast<const float4*>(Y)[i4];
    float4 xv = reinterpret_cast<const float4*>(x)[i4];
    uchar4 av = reinterpret_cast<const uchar4*>(ares)[i4];
    float2 s = st[o];
    float gg = g[o], bb = bet[o];
    float4 r;
    {
        float x1;
        x1 = xv.x + (float)av.x; r.x = x1 + (spike_f32(y.x, s, gg, bb) ? 1.0f : 0.0f);
        x1 = xv.y + (float)av.y; r.y = x1 + (spike_f32(y.y, s, gg, bb) ? 1.0f : 0.0f);
        x1 = xv.z + (float)av.z; r.z = x1 + (spike_f32(y.z, s, gg, bb) ? 1.0f : 0.0f);
        x1 = xv.w + (float)av.w; r.w = x1 + (spike_f32(y.w, s, gg, bb) ? 1.0f : 0.0f);
    }
    reinterpret_cast<float4*>(Out)[i4] = r;
}

extern "C" void kernel_launch(void* const* d_in, const int* in_sizes, int n_in,
                              void* d_out, int out_size, void* d_ws, size_t ws_size,
                              hipStream_t stream)
{
    const float* x         = (const float*)d_in[0];
    const float* q_w       = (const float*)d_in[1];
    const float* q_g       = (const float*)d_in[2];
    const float* q_b       = (const float*)d_in[3];
    const float* k_w       = (const float*)d_in[4];
    const float* k_g       = (const float*)d_in[5];
    const float* k_b       = (const float*)d_in[6];
    const float* v_w       = (const float*)d_in[7];
    const float* v_g       = (const float*)d_in[8];
    const float* v_b       = (const float*)d_in[9];
    const float* proj_w    = (const float*)d_in[10];
    const float* proj_bias = (const float*)d_in[11];
    const float* proj_g    = (const float*)d_in[12];
    const float* proj_b    = (const float*)d_in[13];
    const float* fc1_w     = (const float*)d_in[14];
    const float* fc1_bias  = (const float*)d_in[15];
    const float* fc1_g     = (const float*)d_in[16];
    const float* fc1_b     = (const float*)d_in[17];
    const float* fc2_w     = (const float*)d_in[18];
    const float* fc2_bias  = (const float*)d_in[19];
    const float* fc2_g     = (const float*)d_in[20];
    const float* fc2_b     = (const float*)d_in[21];
    float* out = (float*)d_out;

    char* ws = (char*)d_ws;
    const size_t MiB = 1ull << 20;
    if (ws_size < 124 * MiB) return;

    // ---- layout (124 MiB), phase-checked lifetimes ----
    // Phase qkv : Yq 0-96 | qb 96-104 | kb 104-112 | vb 112-120 | Wtq 120-123 | stats 123+
    // Phase attn: Mpart 16-32 (Yq dead) | Mbuf 120-122 (Wtq dead) | ab 0-8
    // Phase proj: Wt 104-108, bits 108-112 (kb/vb dead) | Af 0-64 | ares 64-72
    // Phase fc1 : Wtf = Wt region 104-108 (proj Wt dead) | Af 0-64 | hb 72-104 (qb dead)
    // Phase fc2 : Wt 104-108 (Wtf dead), bits 108-112 | Af 0-64 | final reads ares 64-72
    float*    Yq    = (float*)(ws);                  // 96 MiB fused qkv out
    float*    Af    = (float*)(ws);                  // 64 MiB GEMM out (later phases)
    uint8_t*  ab    = (uint8_t*)(ws);                //  8 MiB attention spikes
    float*    Mpart = (float*)(ws + 16 * MiB);       // 16 MiB ktv partials (attn phase)
    uint8_t*  ares  = (uint8_t*)(ws + 64 * MiB);     //  8 MiB proj spikes, live to end
    uint8_t*  hb    = (uint8_t*)(ws + 72 * MiB);     // 32 MiB fc1 spikes (72..104)
    uint8_t*  qb    = (uint8_t*)(ws + 96 * MiB);     //  8 MiB [B,H,N,D]
    uint8_t*  kb    = (uint8_t*)(ws + 104 * MiB);    //  8 MiB
    uint8_t*  vb    = (uint8_t*)(ws + 112 * MiB);    //  8 MiB
    float*    Wt    = (float*)(ws + 104 * MiB);      //  4 MiB (sparse Wt / fc1 Wtf)
    unsigned long long* bits = (unsigned long long*)(ws + 108 * MiB);  // 4 MiB
    float*    Wtq   = (float*)(ws + 120 * MiB);      //  3 MiB qkv weights transposed [512][1536]
    float*    Mbuf  = (float*)(ws + 120 * MiB);      //  2 MiB (attn phase, Wtq dead)
    float2*   stats = (float2*)(ws + 123 * MiB);     // 12 KiB (1536 ch max)

    dim3 thr256(256);

    // --- fused q|k|v dense GEMM, SGPR-A: build Wtq[k][1536] (bit-exact transpose) ---
    wt_k<<<dim3(16, 16), thr256, 0, stream>>>(q_w, Wtq, 512, 512,    0, 1536);
    wt_k<<<dim3(16, 16), thr256, 0, stream>>>(k_w, Wtq, 512, 512,  512, 1536);
    wt_k<<<dim3(16, 16), thr256, 0, stream>>>(v_w, Wtq, 512, 512, 1024, 1536);
    gemm_k<0><<<dim3(8, 12, 16), thr256, 0, stream>>>(Wtq, x, nullptr, nullptr, Yq,
                                                      1536, 512, 1024, 1536);
    bn_stats_np_k<<<dim3(1536), dim3(64), 0, stream>>>(Yq, 1536, stats);
    spike_pack_qkv_k<<<dim3(16, 24, 16), thr256, 0, stream>>>(Yq, stats, q_g, k_g, v_g,
                                                              q_b, k_b, v_b, qb, kb, vb);

    // --- attention (exact integers; ktv split 8x for occupancy) ---
    ktv_part_k<<<dim3(128, 8), thr256, 0, stream>>>(kb, vb, Mpart);
    ktv_reduce_k<<<dim3(128), thr256, 0, stream>>>(Mpart, Mbuf);
    attn_spike_k<<<dim3(16, 8, 16), thr256, 0, stream>>>(qb, Mbuf, ab);

    // --- proj (sparse binary-input GEMM) ---
    wt_k<<<dim3(16, 16), thr256, 0, stream>>>(proj_w, Wt, 512, 512, 0, 512);
    col_bits_k<<<dim3(16, 8, 16), thr256, 0, stream>>>(ab, bits, 512);
    sparse_gemm_k<<<dim3(4096), thr256, 0, stream>>>(Wt, bits, proj_bias, Af, 512);
    bn_stats_np_k<<<dim3(512), dim3(64), 0, stream>>>(Af, 512, stats);
    spike_store_k<<<dim3(8192), thr256, 0, stream>>>(Af, stats, proj_g, proj_b, ares, 512, 0, 512);

    // --- fc1 on x1 = f32(x + ares), dense, SGPR-A: Wtf[512][2048] ---
    wt_k<<<dim3(16, 64), thr256, 0, stream>>>(fc1_w, Wt, 2048, 512, 0, 2048);
    for (int ch = 0; ch < 2; ++ch) {
        gemm_k<2><<<dim3(8, 8, 16), thr256, 0, stream>>>(Wt + ch * 1024, x, ares,
                                                         fc1_bias + ch * 1024, Af,
                                                         1024, 512, 1024, 2048);
        bn_stats_np_k<<<dim3(1024), dim3(64), 0, stream>>>(Af, 1024, stats);
        spike_store_k<<<dim3(16384), thr256, 0, stream>>>(Af, stats, fc1_g + ch * 1024, fc1_b + ch * 1024,
                                                          hb, 1024, ch * 1024, 2048);
    }

    // --- fc2 (sparse binary-input GEMM) + final residual ---
    wt_k<<<dim3(64, 16), thr256, 0, stream>>>(fc2_w, Wt, 512, 2048, 0, 512);
    col_bits_k<<<dim3(16, 32, 16), thr256, 0, stream>>>(hb, bits, 2048);
    sparse_gemm_k<<<dim3(4096), thr256, 0, stream>>>(Wt, bits, fc2_bias, Af, 2048);
    bn_stats_np_k<<<dim3(512), dim3(64), 0, stream>>>(Af, 512, stats);
    final_k<<<dim3(8192), thr256, 0, stream>>>(Af, stats, fc2_g, fc2_b, x, ares, out);
}

// Round 7
// 1315.776 us; speedup vs baseline: 1.8994x; 1.6240x over previous
//
#include <hip/hip_runtime.h>
#include <stdint.h>

#pragma clang fp contract(off)

#define BATCH 16
#define CCH   512
#define NLEN  1024
#define NH    8
#define DH    64

// ================= numpy-pairwise emulation (f32, no contraction) =================
__device__ float pw128(const float* __restrict__ x) {
    float r0=x[0],r1=x[1],r2=x[2],r3=x[3],r4=x[4],r5=x[5],r6=x[6],r7=x[7];
    for (int i = 8; i < 128; i += 8) {
        r0 += x[i+0]; r1 += x[i+1]; r2 += x[i+2]; r3 += x[i+3];
        r4 += x[i+4]; r5 += x[i+5]; r6 += x[i+6]; r7 += x[i+7];
    }
    return ((r0+r1)+(r2+r3))+((r4+r5)+(r6+r7));
}
__device__ float pw128_sqdev(const float* __restrict__ x, float m) {
    float r0,r1,r2,r3,r4,r5,r6,r7;
    {
        float d;
        d = x[0]-m; r0 = d*d;  d = x[1]-m; r1 = d*d;
        d = x[2]-m; r2 = d*d;  d = x[3]-m; r3 = d*d;
        d = x[4]-m; r4 = d*d;  d = x[5]-m; r5 = d*d;
        d = x[6]-m; r6 = d*d;  d = x[7]-m; r7 = d*d;
    }
    for (int i = 8; i < 128; i += 8) {
        float d;
        d = x[i+0]-m; r0 += d*d;  d = x[i+1]-m; r1 += d*d;
        d = x[i+2]-m; r2 += d*d;  d = x[i+3]-m; r3 += d*d;
        d = x[i+4]-m; r4 += d*d;  d = x[i+5]-m; r5 += d*d;
        d = x[i+6]-m; r6 += d*d;  d = x[i+7]-m; r7 += d*d;
    }
    return ((r0+r1)+(r2+r3))+((r4+r5)+(r6+r7));
}

// BN stats, numpy semantics (bit-exact). 128 threads: each lane computes ONE pw128 leaf;
// sq[t] = part[2t]+part[2t+1] reproduces the old per-quarter sum exactly; left-fold over
// batches unchanged. 2x wave parallelism vs the 64-thread version.
__global__ __launch_bounds__(128) void bn_stats_np_k(const float* __restrict__ Y, int O,
                                                     float2* __restrict__ st)
{
    const int o = blockIdx.x;
    const int t = threadIdx.x;
    const int bi = t >> 3, h = t & 7;
    __shared__ float part[128];
    __shared__ float sq[64];
    __shared__ float msh;
    const float* p = Y + ((size_t)bi * O + o) * NLEN + h * 128;
    part[t] = pw128(p);
    __syncthreads();
    if (t < 64) sq[t] = part[2 * t] + part[2 * t + 1];   // == pw128(q)+pw128(q+128)
    __syncthreads();
    if (t == 0) {
        float s = 0.0f;
        for (int b = 0; b < 16; ++b) {
            const float* pp = &sq[b * 4];
            float v = (pp[0] + pp[1]) + (pp[2] + pp[3]);
            s = (b == 0) ? v : (s + v);
        }
        msh = s / 16384.0f;
    }
    __syncthreads();
    const float m = msh;
    part[t] = pw128_sqdev(p, m);
    __syncthreads();
    if (t < 64) sq[t] = part[2 * t] + part[2 * t + 1];
    __syncthreads();
    if (t == 0) {
        float s = 0.0f;
        for (int b = 0; b < 16; ++b) {
            const float* pp = &sq[b * 4];
            float v = (pp[0] + pp[1]) + (pp[2] + pp[3]);
            s = (b == 0) ? v : (s + v);
        }
        float var = s / 16384.0f;
        float ve  = var + 1e-5f;
        float sqv = (float)sqrt((double)ve);    // correctly-rounded f32 sqrt
        float r   = (float)(1.0 / (double)sqv); // correctly-rounded f32 reciprocal
        st[o] = make_float2(m, r);
    }
}

// spike of bn output, f32 reference op order
__device__ inline bool spike_f32(float y, float2 s, float g, float b) {
    float t1 = y - s.x;
    float t2 = t1 * s.y;
    float t3 = t2 * g;
    float t4 = t3 + b;
    float u  = t4 / 2.0f - 1.0f;
    return u >= 0.0f;
}

// ===== Dense GEMM (r13 = r9 revival): 128x128 tile, 256 thr, 8x8/thread, BK=16 dbuf =====
// r9 measured 313us, VGPR 96, no spill — the only regalloc-stable configuration found
// (r7/r10/r11/r12 all regressed: bounds-capped spill, VMEM-heuristic 64-VGPR, scalar-load
// latency). Both operands in LDS; A and B reads are 16-way-broadcast b128s.
// Bit-exactness: per output strict ascending-k sequential fmaf chain; bias added once.
// MODE 0: fused qkv — W selected by blockIdx.y (0-3 Wq, 4-7 Wk, 8-11 Wv), X = Xf.
// MODE 2: single W (Wq arg), X = f32(Xf + Xs8).
template<int MODE>
__global__ __launch_bounds__(256) void gemm_k(
    const float* __restrict__ Wq, const float* __restrict__ Wk, const float* __restrict__ Wv,
    const float* __restrict__ Xf, const uint8_t* __restrict__ Xs8,
    const float* __restrict__ bias, float* __restrict__ Y,
    int O, int Cin, int N)
{
    __shared__ float Ws[2][16][132];
    __shared__ float Xs[2][16][132];
    const int b = blockIdx.z;
    const size_t xbase = (size_t)b * Cin * N;
    float* Yb = Y + (size_t)b * O * N;
    const int oy  = blockIdx.y;
    const int o0y = oy * 128;
    const float* W;
    int o0w;
    if (MODE == 0) {
        W   = (oy < 4) ? Wq : (oy < 8) ? Wk : Wv;
        o0w = (oy & 3) * 128;
    } else {
        W   = Wq;
        o0w = o0y;
    }
    const int n0 = blockIdx.x * 128;
    const int t  = threadIdx.x;
    const int tx = t & 15;        // n-group
    const int ty = t >> 4;        // o-group 0..15

    const int wr = t >> 1;          // o-row 0..127
    const int wk = (t & 1) << 3;    // k-subgroup: 0 or 8
    const int xk = t >> 4;          // k-row 0..15
    const int xc = (t & 15) << 3;   // n-offset 0,8,...,120

    float acc[8][8];
#pragma unroll
    for (int i = 0; i < 8; ++i)
#pragma unroll
        for (int j = 0; j < 8; ++j) acc[i][j] = 0.0f;

    float4 wA[2];
    float  xr[8];

    auto loadG = [&](int k0) {
        const float* wp = W + (size_t)(o0w + wr) * Cin + k0 + wk;
        wA[0] = *reinterpret_cast<const float4*>(wp);
        wA[1] = *reinterpret_cast<const float4*>(wp + 4);
        size_t off = xbase + (size_t)(k0 + xk) * N + n0 + xc;
        float4 v0 = *reinterpret_cast<const float4*>(Xf + off);
        float4 v1 = *reinterpret_cast<const float4*>(Xf + off + 4);
        if (MODE == 0) {
            xr[0]=v0.x; xr[1]=v0.y; xr[2]=v0.z; xr[3]=v0.w;
            xr[4]=v1.x; xr[5]=v1.y; xr[6]=v1.z; xr[7]=v1.w;
        } else {
            uchar4 u0 = *reinterpret_cast<const uchar4*>(Xs8 + off);
            uchar4 u1 = *reinterpret_cast<const uchar4*>(Xs8 + off + 4);
            xr[0]=v0.x+(float)u0.x; xr[1]=v0.y+(float)u0.y;
            xr[2]=v0.z+(float)u0.z; xr[3]=v0.w+(float)u0.w;
            xr[4]=v1.x+(float)u1.x; xr[5]=v1.y+(float)u1.y;
            xr[6]=v1.z+(float)u1.z; xr[7]=v1.w+(float)u1.w;
        }
    };
    auto stage = [&](int buf) {
        Ws[buf][wk+0][wr]=wA[0].x; Ws[buf][wk+1][wr]=wA[0].y;
        Ws[buf][wk+2][wr]=wA[0].z; Ws[buf][wk+3][wr]=wA[0].w;
        Ws[buf][wk+4][wr]=wA[1].x; Ws[buf][wk+5][wr]=wA[1].y;
        Ws[buf][wk+6][wr]=wA[1].z; Ws[buf][wk+7][wr]=wA[1].w;
        *reinterpret_cast<float4*>(&Xs[buf][xk][xc])     = make_float4(xr[0],xr[1],xr[2],xr[3]);
        *reinterpret_cast<float4*>(&Xs[buf][xk][xc + 4]) = make_float4(xr[4],xr[5],xr[6],xr[7]);
    };

    loadG(0);
    stage(0);
    __syncthreads();
    int cur = 0;
    for (int k0 = 0;;) {
        const int kn = k0 + 16;
        const bool more = kn < Cin;
        if (more) loadG(kn);            // issue next-tile global loads early
#pragma unroll
        for (int kk = 0; kk < 16; ++kk) {
            float4 a0 = *reinterpret_cast<const float4*>(&Ws[cur][kk][ty * 4]);
            float4 a1 = *reinterpret_cast<const float4*>(&Ws[cur][kk][64 + ty * 4]);
            float4 b0 = *reinterpret_cast<const float4*>(&Xs[cur][kk][tx * 4]);
            float4 b1 = *reinterpret_cast<const float4*>(&Xs[cur][kk][64 + tx * 4]);
            float av[8] = {a0.x,a0.y,a0.z,a0.w,a1.x,a1.y,a1.z,a1.w};
            float bv[8] = {b0.x,b0.y,b0.z,b0.w,b1.x,b1.y,b1.z,b1.w};
#pragma unroll
            for (int i = 0; i < 8; ++i)
#pragma unroll
                for (int j = 0; j < 8; ++j)
                    acc[i][j] = fmaf(av[i], bv[j], acc[i][j]);
        }
        if (!more) break;
        stage(cur ^ 1);                 // overlaps other waves' compute on buf[cur]
        __syncthreads();                // single barrier per K-step
        cur ^= 1;
        k0 = kn;
    }
#pragma unroll
    for (int half = 0; half < 2; ++half)
#pragma unroll
        for (int i = 0; i < 4; ++i) {
            const int r = half * 4 + i;
            const int o = o0y + half * 64 + ty * 4 + i;
            const float bb = bias ? bias[o] : 0.0f;
            float* yp = Yb + (size_t)o * N + n0;
            float4 r0, r1;
            r0.x = acc[r][0] + bb; r0.y = acc[r][1] + bb;
            r0.z = acc[r][2] + bb; r0.w = acc[r][3] + bb;
            r1.x = acc[r][4] + bb; r1.y = acc[r][5] + bb;
            r1.z = acc[r][6] + bb; r1.w = acc[r][7] + bb;
            *reinterpret_cast<float4*>(yp + tx * 4)      = r0;
            *reinterpret_cast<float4*>(yp + 64 + tx * 4) = r1;
        }
}

// ====== W transpose: Wt[k][o_off+o] = W[o][k] (bit-exact copy), column-offset variant ======
__global__ __launch_bounds__(256) void wt_k(const float* __restrict__ W, float* __restrict__ Wt,
                                            int O, int Cin, int o_off, int Otot)
{
    __shared__ float tile[32][33];
    const int k0 = blockIdx.x * 32, o0 = blockIdx.y * 32;
    const int tx = threadIdx.x & 31, ty = threadIdx.x >> 5;  // ty 0..7
#pragma unroll
    for (int j = 0; j < 4; ++j)
        tile[ty + 8*j][tx] = W[(size_t)(o0 + ty + 8*j) * Cin + k0 + tx];
    __syncthreads();
#pragma unroll
    for (int j = 0; j < 4; ++j)
        Wt[(size_t)(k0 + ty + 8*j) * Otot + o_off + o0 + tx] = tile[tx][ty + 8*j];
}

// ================= bit-pack spike columns: bits[b][n][k/64] (bit k%64) =================
__global__ __launch_bounds__(256) void col_bits_k(const uint8_t* __restrict__ S,
                                                  unsigned long long* __restrict__ bits, int Cin)
{
    // grid: (N/64, Cin/64, B)
    const int n0 = blockIdx.x * 64, kw = blockIdx.y, b = blockIdx.z;
    __shared__ uint8_t tile[64][64];   // [k][n], rows 64 B -> 16B-aligned
    const int t = threadIdx.x;
    const int r = t >> 2, cg = (t & 3) * 16;
    const uint8_t* src = S + ((size_t)b * Cin + kw * 64 + r) * NLEN + n0 + cg;
    *reinterpret_cast<uint4*>(&tile[r][cg]) = *reinterpret_cast<const uint4*>(src);
    __syncthreads();
    if (t < 64) {
        unsigned long long m = 0;
#pragma unroll
        for (int rr = 0; rr < 64; ++rr)
            m |= ((unsigned long long)(tile[rr][t] != 0)) << rr;
        bits[((size_t)b * NLEN + n0 + t) * (Cin >> 6) + kw] = m;
    }
}

// ================= sparse GEMM (binary X): one wave per (b,n) column, O=512 =================
__global__ __launch_bounds__(256) void sparse_gemm_k(
    const float* __restrict__ Wt, const unsigned long long* __restrict__ bits,
    const float* __restrict__ bias, float* __restrict__ Y, int Cin)
{
    const int wid  = (blockIdx.x << 2) + (threadIdx.x >> 6);
    const int lane = threadIdx.x & 63;
    const int b = wid >> 10, n = wid & 1023;
    const int W64 = Cin >> 6;
    float acc[8];
#pragma unroll
    for (int i = 0; i < 8; ++i) acc[i] = 0.0f;
    const unsigned long long* bp = bits + ((size_t)b * NLEN + n) * W64;
    for (int w = 0; w < W64; ++w) {
        unsigned long long m = bp[w];
        while (m) {
            const int bit = __builtin_ctzll(m);
            m &= m - 1;
            const int k = (w << 6) + bit;
            const float* wr = Wt + ((size_t)k << 9) + lane * 8;  // O=512
            float4 w0 = *reinterpret_cast<const float4*>(wr);
            float4 w1 = *reinterpret_cast<const float4*>(wr + 4);
            acc[0] += w0.x; acc[1] += w0.y; acc[2] += w0.z; acc[3] += w0.w;
            acc[4] += w1.x; acc[5] += w1.y; acc[6] += w1.z; acc[7] += w1.w;
        }
    }
    const float* bq = bias + lane * 8;
    float4 b0 = *reinterpret_cast<const float4*>(bq);
    float4 b1 = *reinterpret_cast<const float4*>(bq + 4);
    float bi[8] = {b0.x, b0.y, b0.z, b0.w, b1.x, b1.y, b1.z, b1.w};
    float* yp = Y + ((size_t)b * 512 + lane * 8) * NLEN + n;
#pragma unroll
    for (int i = 0; i < 8; ++i)
        yp[(size_t)i * NLEN] = acc[i] + bi[i];
}

// ======== fused qkv spike + transpose to [B,H,N,D] u8 (selects tensor by blockIdx.y) ========
__global__ __launch_bounds__(256) void spike_pack_qkv_k(
    const float* __restrict__ Y, const float2* __restrict__ st,
    const float* __restrict__ gq, const float* __restrict__ gk, const float* __restrict__ gv,
    const float* __restrict__ bq, const float* __restrict__ bk, const float* __restrict__ bv,
    uint8_t* __restrict__ oq, uint8_t* __restrict__ ok, uint8_t* __restrict__ ov)
{
    const int nt = blockIdx.x, hs = blockIdx.y, b = blockIdx.z;  // hs 0..23
    const int tensor = hs >> 3, h = hs & 7;
    const float* g  = (tensor == 0) ? gq : (tensor == 1) ? gk : gv;
    const float* be = (tensor == 0) ? bq : (tensor == 1) ? bk : bv;
    uint8_t* outp   = (tensor == 0) ? oq : (tensor == 1) ? ok : ov;
    __shared__ uint8_t tile[64][68];
    const int t = threadIdx.x;
    {
        const int i = t & 63, dq = t >> 6;
#pragma unroll
        for (int p = 0; p < 16; ++p) {
            int d  = dq * 16 + p;
            int cf = hs * 64 + d;            // fused channel 0..1535
            int cl = h * 64 + d;             // per-tensor channel 0..511
            float y = Y[((size_t)b * 1536 + cf) * NLEN + nt * 64 + i];
            tile[d][i] = spike_f32(y, st[cf], g[cl], be[cl]) ? 1 : 0;
        }
    }
    __syncthreads();
    {
        const int d4 = (t & 15) * 4, ig = t >> 4;   // uchar4 stores: 4B/lane/instr
        uint8_t* ob = outp + ((size_t)(b * NH + h) * NLEN + nt * 64) * DH;
#pragma unroll
        for (int p = 0; p < 4; ++p) {
            int i = p * 16 + ig;
            uchar4 v;
            v.x = tile[d4 + 0][i]; v.y = tile[d4 + 1][i];
            v.z = tile[d4 + 2][i]; v.w = tile[d4 + 3][i];
            *reinterpret_cast<uchar4*>(ob + (size_t)i * DH + d4) = v;
        }
    }
}

// ====== M partial = K^T V over a 128-position chunk (integers exact in f32) ======
// grid (BH=128, 8 chunks): full GPU. Staging via uint4 loads (1 instr replaces 16).
__global__ __launch_bounds__(256) void ktv_part_k(const uint8_t* __restrict__ Kb,
                                                  const uint8_t* __restrict__ Vb,
                                                  float* __restrict__ Mp)
{
    const int bh = blockIdx.x, ch = blockIdx.y;
    const uint8_t* kp = Kb + (size_t)bh * NLEN * DH;
    const uint8_t* vp = Vb + (size_t)bh * NLEN * DH;
    __shared__ float ks[64][68];
    __shared__ float vs[64][68];
    const int t = threadIdx.x;
    const int d2 = t & 63, g4 = t >> 6;
    const int r2 = t >> 2, dq = (t & 3) * 16;
    float acc[16];
#pragma unroll
    for (int j = 0; j < 16; ++j) acc[j] = 0.f;

    for (int nc = ch * 128; nc < ch * 128 + 128; nc += 64) {
        uint4 kv = *reinterpret_cast<const uint4*>(kp + (size_t)(nc + r2) * DH + dq);
        uint4 vv = *reinterpret_cast<const uint4*>(vp + (size_t)(nc + r2) * DH + dq);
        const uint8_t* k8 = reinterpret_cast<const uint8_t*>(&kv);
        const uint8_t* v8 = reinterpret_cast<const uint8_t*>(&vv);
#pragma unroll
        for (int j = 0; j < 16; j += 4) {
            float4 kf, vf;
            kf.x = (float)k8[j+0]; kf.y = (float)k8[j+1];
            kf.z = (float)k8[j+2]; kf.w = (float)k8[j+3];
            vf.x = (float)v8[j+0]; vf.y = (float)v8[j+1];
            vf.z = (float)v8[j+2]; vf.w = (float)v8[j+3];
            *reinterpret_cast<float4*>(&ks[r2][dq + j]) = kf;
            *reinterpret_cast<float4*>(&vs[r2][dq + j]) = vf;
        }
        __syncthreads();
        for (int n = 0; n < 64; ++n) {
            float vvv = vs[n][d2];
#pragma unroll
            for (int j = 0; j < 16; ++j)
                acc[j] += ks[n][g4 * 16 + j] * vvv;
        }
        __syncthreads();
    }
#pragma unroll
    for (int j = 0; j < 16; ++j)
        Mp[((size_t)ch * 128 + bh) * 4096 + (size_t)(g4 * 16 + j) * 64 + d2] = acc[j];
}

// ====== M = sum of 8 integer partials (exact in f32, order-free) ======
__global__ __launch_bounds__(256) void ktv_reduce_k(const float* __restrict__ Mp,
                                                    float* __restrict__ M)
{
    const int bh = blockIdx.x;
    const int t = threadIdx.x;
#pragma unroll
    for (int j = 0; j < 16; j += 4) {
        const int idx = t * 16 + j;
        float4 s = *reinterpret_cast<const float4*>(&Mp[(size_t)bh * 4096 + idx]);
#pragma unroll
        for (int c = 1; c < 8; ++c) {
            float4 v = *reinterpret_cast<const float4*>(&Mp[((size_t)c * 128 + bh) * 4096 + idx]);
            s.x += v.x; s.y += v.y; s.z += v.z; s.w += v.w;
        }
        *reinterpret_cast<float4*>(&M[(size_t)bh * 4096 + idx]) = s;
    }
}

// ================= attn = Q @ M, integer spike attn>=8, write [B,C,N] u8 =================
__global__ __launch_bounds__(256) void attn_spike_k(const uint8_t* __restrict__ Qb, const float* __restrict__ M,
                                                    uint8_t* __restrict__ A)
{
    const int nt = blockIdx.x, h = blockIdx.y, b = blockIdx.z;
    const int bh = b * NH + h;
    __shared__ float Ms[64][68];
    __shared__ float qs[64][65];
    const int t = threadIdx.x;
    const int r2 = t >> 2, cq = (t & 3) * 16;
    {
        // M: 4x float4 loads; Q: 1 uint4 load + transpose-write
        const float* mp = M + (size_t)bh * 4096 + (size_t)r2 * 64 + cq;
#pragma unroll
        for (int u = 0; u < 4; ++u)
            *reinterpret_cast<float4*>(&Ms[r2][cq + 4 * u]) =
                *reinterpret_cast<const float4*>(mp + 4 * u);
        uint4 qv = *reinterpret_cast<const uint4*>(
            Qb + ((size_t)bh * NLEN + nt * 64 + r2) * DH + cq);
        const uint8_t* q8 = reinterpret_cast<const uint8_t*>(&qv);
#pragma unroll
        for (int j = 0; j < 16; ++j)
            qs[cq + j][r2] = (float)q8[j];
    }
    __syncthreads();
    const int n = t & 63, dg = t >> 6;
    float acc[16];
#pragma unroll
    for (int j = 0; j < 16; ++j) acc[j] = 0.f;
    for (int d1 = 0; d1 < 64; ++d1) {
        float qv = qs[d1][n];
#pragma unroll
        for (int j = 0; j < 16; ++j)
            acc[j] += qv * Ms[d1][dg * 16 + j];
    }
#pragma unroll
    for (int j = 0; j < 16; ++j) {
        int d = dg * 16 + j;
        A[((size_t)b * CCH + h * 64 + d) * NLEN + nt * 64 + n] = (acc[j] >= 8.0f) ? 1 : 0;
    }
}

// ================= spike -> u8 store at channel offset =================
__global__ __launch_bounds__(256) void spike_store_k(
    const float* __restrict__ Y, const float2* __restrict__ st,
    const float* __restrict__ g, const float* __restrict__ bet,
    uint8_t* __restrict__ H, int Oc, int o_off, int Otot)
{
    size_t i4 = (size_t)blockIdx.x * 256 + threadIdx.x;
    size_t total = (size_t)BATCH * Oc * (NLEN / 4);
    if (i4 >= total) return;
    int n4 = (int)(i4 & 255);
    int o  = (int)((i4 >> 8) % Oc);
    int b  = (int)(i4 / ((size_t)256 * Oc));
    float4 y = reinterpret_cast<const float4*>(Y)[i4];
    float2 s = st[o];
    float gg = g[o], bb = bet[o];
    uchar4 r;
    r.x = spike_f32(y.x, s, gg, bb) ? 1 : 0;
    r.y = spike_f32(y.y, s, gg, bb) ? 1 : 0;
    r.z = spike_f32(y.z, s, gg, bb) ? 1 : 0;
    r.w = spike_f32(y.w, s, gg, bb) ? 1 : 0;
    *reinterpret_cast<uchar4*>(H + ((size_t)(b * Otot + o_off + o)) * NLEN + n4 * 4) = r;
}

// ================= out = (x + ares) + spike(bn(Y)) in np f32 order =================
__global__ __launch_bounds__(256) void final_k(
    const float* __restrict__ Y, const float2* __restrict__ st,
    const float* __restrict__ g, const float* __restrict__ bet,
    const float* __restrict__ x, const uint8_t* __restrict__ ares,
    float* __restrict__ Out)
{
    size_t i4 = (size_t)blockIdx.x * 256 + threadIdx.x;
    size_t total = (size_t)BATCH * CCH * (NLEN / 4);
    if (i4 >= total) return;
    int o = (int)((i4 >> 8) % CCH);
    float4 y  = reinterpret_cast<const float4*>(Y)[i4];
    float4 xv = reinterpret_cast<const float4*>(x)[i4];
    uchar4 av = reinterpret_cast<const uchar4*>(ares)[i4];
    float2 s = st[o];
    float gg = g[o], bb = bet[o];
    float4 r;
    {
        float x1;
        x1 = xv.x + (float)av.x; r.x = x1 + (spike_f32(y.x, s, gg, bb) ? 1.0f : 0.0f);
        x1 = xv.y + (float)av.y; r.y = x1 + (spike_f32(y.y, s, gg, bb) ? 1.0f : 0.0f);
        x1 = xv.z + (float)av.z; r.z = x1 + (spike_f32(y.z, s, gg, bb) ? 1.0f : 0.0f);
        x1 = xv.w + (float)av.w; r.w = x1 + (spike_f32(y.w, s, gg, bb) ? 1.0f : 0.0f);
    }
    reinterpret_cast<float4*>(Out)[i4] = r;
}

extern "C" void kernel_launch(void* const* d_in, const int* in_sizes, int n_in,
                              void* d_out, int out_size, void* d_ws, size_t ws_size,
                              hipStream_t stream)
{
    const float* x         = (const float*)d_in[0];
    const float* q_w       = (const float*)d_in[1];
    const float* q_g       = (const float*)d_in[2];
    const float* q_b       = (const float*)d_in[3];
    const float* k_w       = (const float*)d_in[4];
    const float* k_g       = (const float*)d_in[5];
    const float* k_b       = (const float*)d_in[6];
    const float* v_w       = (const float*)d_in[7];
    const float* v_g       = (const float*)d_in[8];
    const float* v_b       = (const float*)d_in[9];
    const float* proj_w    = (const float*)d_in[10];
    const float* proj_bias = (const float*)d_in[11];
    const float* proj_g    = (const float*)d_in[12];
    const float* proj_b    = (const float*)d_in[13];
    const float* fc1_w     = (const float*)d_in[14];
    const float* fc1_bias  = (const float*)d_in[15];
    const float* fc1_g     = (const float*)d_in[16];
    const float* fc1_b     = (const float*)d_in[17];
    const float* fc2_w     = (const float*)d_in[18];
    const float* fc2_bias  = (const float*)d_in[19];
    const float* fc2_g     = (const float*)d_in[20];
    const float* fc2_b     = (const float*)d_in[21];
    float* out = (float*)d_out;

    char* ws = (char*)d_ws;
    const size_t MiB = 1ull << 20;
    if (ws_size < 124 * MiB) return;

    // ---- layout (124 MiB), phase-checked lifetimes ----
    // Phase qkv : Yq 0-96 | qb 96-104 | kb 104-112 | vb 112-120 | stats 123+
    // Phase attn: Mpart 16-32 (Yq dead) | Mbuf 120-122 | ab 0-8
    // Phase proj: Wt 104-108, bits 108-112 (kb/vb dead) | Af 0-64 | ares 64-72
    // Phase fc1 : Af 0-64 | hb 72-104 (qb dead)
    // Phase fc2 : Wt 104-108, bits 108-112 | Af 0-64 | final reads ares 64-72
    float*    Yq    = (float*)(ws);                  // 96 MiB fused qkv out
    float*    Af    = (float*)(ws);                  // 64 MiB GEMM out (later phases)
    uint8_t*  ab    = (uint8_t*)(ws);                //  8 MiB attention spikes
    float*    Mpart = (float*)(ws + 16 * MiB);       // 16 MiB ktv partials (attn phase)
    uint8_t*  ares  = (uint8_t*)(ws + 64 * MiB);     //  8 MiB proj spikes, live to end
    uint8_t*  hb    = (uint8_t*)(ws + 72 * MiB);     // 32 MiB fc1 spikes (72..104)
    uint8_t*  qb    = (uint8_t*)(ws + 96 * MiB);     //  8 MiB [B,H,N,D]
    uint8_t*  kb    = (uint8_t*)(ws + 104 * MiB);    //  8 MiB
    uint8_t*  vb    = (uint8_t*)(ws + 112 * MiB);    //  8 MiB
    float*    Wt    = (float*)(ws + 104 * MiB);      //  4 MiB (sparse Wt; kb dead by proj)
    unsigned long long* bits = (unsigned long long*)(ws + 108 * MiB);  // 4 MiB
    float*    Mbuf  = (float*)(ws + 120 * MiB);      //  2 MiB (attn phase)
    float2*   stats = (float2*)(ws + 123 * MiB);     // 12 KiB (1536 ch max)

    dim3 thr256(256), thr128(128);

    // --- fused q|k|v dense GEMM: W selected per-block, no weight copies ---
    gemm_k<0><<<dim3(8, 12, 16), thr256, 0, stream>>>(q_w, k_w, v_w, x, nullptr, nullptr, Yq,
                                                      1536, 512, 1024);
    bn_stats_np_k<<<dim3(1536), thr128, 0, stream>>>(Yq, 1536, stats);
    spike_pack_qkv_k<<<dim3(16, 24, 16), thr256, 0, stream>>>(Yq, stats, q_g, k_g, v_g,
                                                              q_b, k_b, v_b, qb, kb, vb);

    // --- attention (exact integers; ktv split 8x for occupancy) ---
    ktv_part_k<<<dim3(128, 8), thr256, 0, stream>>>(kb, vb, Mpart);
    ktv_reduce_k<<<dim3(128), thr256, 0, stream>>>(Mpart, Mbuf);
    attn_spike_k<<<dim3(16, 8, 16), thr256, 0, stream>>>(qb, Mbuf, ab);

    // --- proj (sparse binary-input GEMM) ---
    wt_k<<<dim3(16, 16), thr256, 0, stream>>>(proj_w, Wt, 512, 512, 0, 512);
    col_bits_k<<<dim3(16, 8, 16), thr256, 0, stream>>>(ab, bits, 512);
    sparse_gemm_k<<<dim3(4096), thr256, 0, stream>>>(Wt, bits, proj_bias, Af, 512);
    bn_stats_np_k<<<dim3(512), thr128, 0, stream>>>(Af, 512, stats);
    spike_store_k<<<dim3(8192), thr256, 0, stream>>>(Af, stats, proj_g, proj_b, ares, 512, 0, 512);

    // --- fc1 on x1 = f32(x + ares), dense, 2 chunks of 1024 out-ch ---
    for (int ch = 0; ch < 2; ++ch) {
        const float* Wc = fc1_w + (size_t)ch * 1024 * 512;
        gemm_k<2><<<dim3(8, 8, 16), thr256, 0, stream>>>(Wc, Wc, Wc, x, ares,
                                                         fc1_bias + ch * 1024, Af,
                                                         1024, 512, 1024);
        bn_stats_np_k<<<dim3(1024), thr128, 0, stream>>>(Af, 1024, stats);
        spike_store_k<<<dim3(16384), thr256, 0, stream>>>(Af, stats, fc1_g + ch * 1024, fc1_b + ch * 1024,
                                                          hb, 1024, ch * 1024, 2048);
    }

    // --- fc2 (sparse binary-input GEMM) + final residual ---
    wt_k<<<dim3(64, 16), thr256, 0, stream>>>(fc2_w, Wt, 512, 2048, 0, 512);
    col_bits_k<<<dim3(16, 32, 16), thr256, 0, stream>>>(hb, bits, 2048);
    sparse_gemm_k<<<dim3(4096), thr256, 0, stream>>>(Wt, bits, fc2_bias, Af, 2048);
    bn_stats_np_k<<<dim3(512), thr128, 0, stream>>>(Af, 512, stats);
    final_k<<<dim3(8192), thr256, 0, stream>>>(Af, stats, fc2_g, fc2_b, x, ares, out);
}

// Round 8
// 1310.434 us; speedup vs baseline: 1.9072x; 1.0041x over previous
//
#include <hip/hip_runtime.h>
#include <stdint.h>

#pragma clang fp contract(off)

#define BATCH 16
#define CCH   512
#define NLEN  1024
#define NH    8
#define DH    64

// ================= numpy-pairwise emulation (f32, no contraction) =================
__device__ float pw128(const float* __restrict__ x) {
    float r0=x[0],r1=x[1],r2=x[2],r3=x[3],r4=x[4],r5=x[5],r6=x[6],r7=x[7];
    for (int i = 8; i < 128; i += 8) {
        r0 += x[i+0]; r1 += x[i+1]; r2 += x[i+2]; r3 += x[i+3];
        r4 += x[i+4]; r5 += x[i+5]; r6 += x[i+6]; r7 += x[i+7];
    }
    return ((r0+r1)+(r2+r3))+((r4+r5)+(r6+r7));
}
__device__ float pw128_sqdev(const float* __restrict__ x, float m) {
    float r0,r1,r2,r3,r4,r5,r6,r7;
    {
        float d;
        d = x[0]-m; r0 = d*d;  d = x[1]-m; r1 = d*d;
        d = x[2]-m; r2 = d*d;  d = x[3]-m; r3 = d*d;
        d = x[4]-m; r4 = d*d;  d = x[5]-m; r5 = d*d;
        d = x[6]-m; r6 = d*d;  d = x[7]-m; r7 = d*d;
    }
    for (int i = 8; i < 128; i += 8) {
        float d;
        d = x[i+0]-m; r0 += d*d;  d = x[i+1]-m; r1 += d*d;
        d = x[i+2]-m; r2 += d*d;  d = x[i+3]-m; r3 += d*d;
        d = x[i+4]-m; r4 += d*d;  d = x[i+5]-m; r5 += d*d;
        d = x[i+6]-m; r6 += d*d;  d = x[i+7]-m; r7 += d*d;
    }
    return ((r0+r1)+(r2+r3))+((r4+r5)+(r6+r7));
}

// BN stats, numpy semantics (bit-exact). 128 threads: each lane computes ONE pw128 leaf;
// sq[t] = part[2t]+part[2t+1] reproduces the old per-quarter sum exactly; left-fold over
// batches unchanged.
__global__ __launch_bounds__(128) void bn_stats_np_k(const float* __restrict__ Y, int O,
                                                     float2* __restrict__ st)
{
    const int o = blockIdx.x;
    const int t = threadIdx.x;
    const int bi = t >> 3, h = t & 7;
    __shared__ float part[128];
    __shared__ float sq[64];
    __shared__ float msh;
    const float* p = Y + ((size_t)bi * O + o) * NLEN + h * 128;
    part[t] = pw128(p);
    __syncthreads();
    if (t < 64) sq[t] = part[2 * t] + part[2 * t + 1];   // == pw128(q)+pw128(q+128)
    __syncthreads();
    if (t == 0) {
        float s = 0.0f;
        for (int b = 0; b < 16; ++b) {
            const float* pp = &sq[b * 4];
            float v = (pp[0] + pp[1]) + (pp[2] + pp[3]);
            s = (b == 0) ? v : (s + v);
        }
        msh = s / 16384.0f;
    }
    __syncthreads();
    const float m = msh;
    part[t] = pw128_sqdev(p, m);
    __syncthreads();
    if (t < 64) sq[t] = part[2 * t] + part[2 * t + 1];
    __syncthreads();
    if (t == 0) {
        float s = 0.0f;
        for (int b = 0; b < 16; ++b) {
            const float* pp = &sq[b * 4];
            float v = (pp[0] + pp[1]) + (pp[2] + pp[3]);
            s = (b == 0) ? v : (s + v);
        }
        float var = s / 16384.0f;
        float ve  = var + 1e-5f;
        float sqv = (float)sqrt((double)ve);    // correctly-rounded f32 sqrt
        float r   = (float)(1.0 / (double)sqv); // correctly-rounded f32 reciprocal
        st[o] = make_float2(m, r);
    }
}

// spike of bn output, f32 reference op order
__device__ inline bool spike_f32(float y, float2 s, float g, float b) {
    float t1 = y - s.x;
    float t2 = t1 * s.y;
    float t3 = t2 * g;
    float t4 = t3 + b;
    float u  = t4 / 2.0f - 1.0f;
    return u >= 0.0f;
}

// ===== Dense GEMM (r14): 128x128 tile, 256 thr, 8x8/thread, BK=8 dbuf =====
// Discriminating change vs r13 (307us, BK=16, LDS 33792, VALUBusy 72%, Occ 21%):
// halve LDS to 16896 B -> LDS-capacity 9 blocks/CU (was 4), wave-slots 8.
// Model A (residency-limited barriers): more independent blocks cover barrier
// drains -> VALUBusy up, time down. Model B (LDS-pipe-bound): neutral.
// acc[8][8]=64 VGPR kept (the only regalloc-stable size: r7/r10/r11 spilled).
// Bit-exactness: per output strict ascending-k sequential fmaf chain; bias once.
// MODE 0: fused qkv — W selected by blockIdx.y (0-3 Wq, 4-7 Wk, 8-11 Wv), X = Xf.
// MODE 2: single W (Wq arg), X = f32(Xf + Xs8).
template<int MODE>
__global__ __launch_bounds__(256) void gemm_k(
    const float* __restrict__ Wq, const float* __restrict__ Wk, const float* __restrict__ Wv,
    const float* __restrict__ Xf, const uint8_t* __restrict__ Xs8,
    const float* __restrict__ bias, float* __restrict__ Y,
    int O, int Cin, int N)
{
    __shared__ float Ws[2][8][132];
    __shared__ float Xs[2][8][132];
    const int b = blockIdx.z;
    const size_t xbase = (size_t)b * Cin * N;
    float* Yb = Y + (size_t)b * O * N;
    const int oy  = blockIdx.y;
    const int o0y = oy * 128;
    const float* W;
    int o0w;
    if (MODE == 0) {
        W   = (oy < 4) ? Wq : (oy < 8) ? Wk : Wv;
        o0w = (oy & 3) * 128;
    } else {
        W   = Wq;
        o0w = o0y;
    }
    const int n0 = blockIdx.x * 128;
    const int t  = threadIdx.x;
    const int tx = t & 15;        // n-group
    const int ty = t >> 4;        // o-group 0..15

    const int wr = t & 127;         // o-row 0..127
    const int wk = (t >> 7) << 2;   // k-offset 0 or 4
    const int xk = t >> 5;          // k-row 0..7
    const int xc = (t & 31) << 2;   // n-offset 0,4,...,124

    float acc[8][8];
#pragma unroll
    for (int i = 0; i < 8; ++i)
#pragma unroll
        for (int j = 0; j < 8; ++j) acc[i][j] = 0.0f;

    float4 wA;
    float  xr[4];

    auto loadG = [&](int k0) {
        const float* wp = W + (size_t)(o0w + wr) * Cin + k0 + wk;
        wA = *reinterpret_cast<const float4*>(wp);
        size_t off = xbase + (size_t)(k0 + xk) * N + n0 + xc;
        float4 v0 = *reinterpret_cast<const float4*>(Xf + off);
        if (MODE == 0) {
            xr[0]=v0.x; xr[1]=v0.y; xr[2]=v0.z; xr[3]=v0.w;
        } else {
            uchar4 u0 = *reinterpret_cast<const uchar4*>(Xs8 + off);
            xr[0]=v0.x+(float)u0.x; xr[1]=v0.y+(float)u0.y;
            xr[2]=v0.z+(float)u0.z; xr[3]=v0.w+(float)u0.w;
        }
    };
    auto stage = [&](int buf) {
        // Ws writes: consecutive wr lanes -> 2 lanes/bank (free)
        Ws[buf][wk+0][wr]=wA.x; Ws[buf][wk+1][wr]=wA.y;
        Ws[buf][wk+2][wr]=wA.z; Ws[buf][wk+3][wr]=wA.w;
        *reinterpret_cast<float4*>(&Xs[buf][xk][xc]) = make_float4(xr[0],xr[1],xr[2],xr[3]);
    };

    loadG(0);
    stage(0);
    __syncthreads();
    int cur = 0;
    for (int k0 = 0;;) {
        const int kn = k0 + 8;
        const bool more = kn < Cin;
        if (more) loadG(kn);            // issue next-tile global loads early
#pragma unroll
        for (int kk = 0; kk < 8; ++kk) {
            float4 a0 = *reinterpret_cast<const float4*>(&Ws[cur][kk][ty * 4]);
            float4 a1 = *reinterpret_cast<const float4*>(&Ws[cur][kk][64 + ty * 4]);
            float4 b0 = *reinterpret_cast<const float4*>(&Xs[cur][kk][tx * 4]);
            float4 b1 = *reinterpret_cast<const float4*>(&Xs[cur][kk][64 + tx * 4]);
            float av[8] = {a0.x,a0.y,a0.z,a0.w,a1.x,a1.y,a1.z,a1.w};
            float bv[8] = {b0.x,b0.y,b0.z,b0.w,b1.x,b1.y,b1.z,b1.w};
#pragma unroll
            for (int i = 0; i < 8; ++i)
#pragma unroll
                for (int j = 0; j < 8; ++j)
                    acc[i][j] = fmaf(av[i], bv[j], acc[i][j]);
        }
        if (!more) break;
        stage(cur ^ 1);                 // overlaps other waves' compute on buf[cur]
        __syncthreads();                // single barrier per K-step
        cur ^= 1;
        k0 = kn;
    }
#pragma unroll
    for (int half = 0; half < 2; ++half)
#pragma unroll
        for (int i = 0; i < 4; ++i) {
            const int r = half * 4 + i;
            const int o = o0y + half * 64 + ty * 4 + i;
            const float bb = bias ? bias[o] : 0.0f;
            float* yp = Yb + (size_t)o * N + n0;
            float4 r0, r1;
            r0.x = acc[r][0] + bb; r0.y = acc[r][1] + bb;
            r0.z = acc[r][2] + bb; r0.w = acc[r][3] + bb;
            r1.x = acc[r][4] + bb; r1.y = acc[r][5] + bb;
            r1.z = acc[r][6] + bb; r1.w = acc[r][7] + bb;
            *reinterpret_cast<float4*>(yp + tx * 4)      = r0;
            *reinterpret_cast<float4*>(yp + 64 + tx * 4) = r1;
        }
}

// ====== W transpose: Wt[k][o_off+o] = W[o][k] (bit-exact copy), column-offset variant ======
__global__ __launch_bounds__(256) void wt_k(const float* __restrict__ W, float* __restrict__ Wt,
                                            int O, int Cin, int o_off, int Otot)
{
    __shared__ float tile[32][33];
    const int k0 = blockIdx.x * 32, o0 = blockIdx.y * 32;
    const int tx = threadIdx.x & 31, ty = threadIdx.x >> 5;  // ty 0..7
#pragma unroll
    for (int j = 0; j < 4; ++j)
        tile[ty + 8*j][tx] = W[(size_t)(o0 + ty + 8*j) * Cin + k0 + tx];
    __syncthreads();
#pragma unroll
    for (int j = 0; j < 4; ++j)
        Wt[(size_t)(k0 + ty + 8*j) * Otot + o_off + o0 + tx] = tile[tx][ty + 8*j];
}

// ================= bit-pack spike columns: bits[b][n][k/64] (bit k%64) =================
__global__ __launch_bounds__(256) void col_bits_k(const uint8_t* __restrict__ S,
                                                  unsigned long long* __restrict__ bits, int Cin)
{
    // grid: (N/64, Cin/64, B)
    const int n0 = blockIdx.x * 64, kw = blockIdx.y, b = blockIdx.z;
    __shared__ uint8_t tile[64][64];   // [k][n], rows 64 B -> 16B-aligned
    const int t = threadIdx.x;
    const int r = t >> 2, cg = (t & 3) * 16;
    const uint8_t* src = S + ((size_t)b * Cin + kw * 64 + r) * NLEN + n0 + cg;
    *reinterpret_cast<uint4*>(&tile[r][cg]) = *reinterpret_cast<const uint4*>(src);
    __syncthreads();
    if (t < 64) {
        unsigned long long m = 0;
#pragma unroll
        for (int rr = 0; rr < 64; ++rr)
            m |= ((unsigned long long)(tile[rr][t] != 0)) << rr;
        bits[((size_t)b * NLEN + n0 + t) * (Cin >> 6) + kw] = m;
    }
}

// ================= sparse GEMM (binary X): one wave per (b,n) column, O=512 =================
__global__ __launch_bounds__(256) void sparse_gemm_k(
    const float* __restrict__ Wt, const unsigned long long* __restrict__ bits,
    const float* __restrict__ bias, float* __restrict__ Y, int Cin)
{
    const int wid  = (blockIdx.x << 2) + (threadIdx.x >> 6);
    const int lane = threadIdx.x & 63;
    const int b = wid >> 10, n = wid & 1023;
    const int W64 = Cin >> 6;
    float acc[8];
#pragma unroll
    for (int i = 0; i < 8; ++i) acc[i] = 0.0f;
    const unsigned long long* bp = bits + ((size_t)b * NLEN + n) * W64;
    for (int w = 0; w < W64; ++w) {
        unsigned long long m = bp[w];
        while (m) {
            const int bit = __builtin_ctzll(m);
            m &= m - 1;
            const int k = (w << 6) + bit;
            const float* wr = Wt + ((size_t)k << 9) + lane * 8;  // O=512
            float4 w0 = *reinterpret_cast<const float4*>(wr);
            float4 w1 = *reinterpret_cast<const float4*>(wr + 4);
            acc[0] += w0.x; acc[1] += w0.y; acc[2] += w0.z; acc[3] += w0.w;
            acc[4] += w1.x; acc[5] += w1.y; acc[6] += w1.z; acc[7] += w1.w;
        }
    }
    const float* bq = bias + lane * 8;
    float4 b0 = *reinterpret_cast<const float4*>(bq);
    float4 b1 = *reinterpret_cast<const float4*>(bq + 4);
    float bi[8] = {b0.x, b0.y, b0.z, b0.w, b1.x, b1.y, b1.z, b1.w};
    float* yp = Y + ((size_t)b * 512 + lane * 8) * NLEN + n;
#pragma unroll
    for (int i = 0; i < 8; ++i)
        yp[(size_t)i * NLEN] = acc[i] + bi[i];
}

// ======== fused qkv spike + transpose to [B,H,N,D] u8 (selects tensor by blockIdx.y) ========
__global__ __launch_bounds__(256) void spike_pack_qkv_k(
    const float* __restrict__ Y, const float2* __restrict__ st,
    const float* __restrict__ gq, const float* __restrict__ gk, const float* __restrict__ gv,
    const float* __restrict__ bq, const float* __restrict__ bk, const float* __restrict__ bv,
    uint8_t* __restrict__ oq, uint8_t* __restrict__ ok, uint8_t* __restrict__ ov)
{
    const int nt = blockIdx.x, hs = blockIdx.y, b = blockIdx.z;  // hs 0..23
    const int tensor = hs >> 3, h = hs & 7;
    const float* g  = (tensor == 0) ? gq : (tensor == 1) ? gk : gv;
    const float* be = (tensor == 0) ? bq : (tensor == 1) ? bk : bv;
    uint8_t* outp   = (tensor == 0) ? oq : (tensor == 1) ? ok : ov;
    __shared__ uint8_t tile[64][68];
    const int t = threadIdx.x;
    {
        const int i = t & 63, dq = t >> 6;
#pragma unroll
        for (int p = 0; p < 16; ++p) {
            int d  = dq * 16 + p;
            int cf = hs * 64 + d;            // fused channel 0..1535
            int cl = h * 64 + d;             // per-tensor channel 0..511
            float y = Y[((size_t)b * 1536 + cf) * NLEN + nt * 64 + i];
            tile[d][i] = spike_f32(y, st[cf], g[cl], be[cl]) ? 1 : 0;
        }
    }
    __syncthreads();
    {
        const int d4 = (t & 15) * 4, ig = t >> 4;   // uchar4 stores: 4B/lane/instr
        uint8_t* ob = outp + ((size_t)(b * NH + h) * NLEN + nt * 64) * DH;
#pragma unroll
        for (int p = 0; p < 4; ++p) {
            int i = p * 16 + ig;
            uchar4 v;
            v.x = tile[d4 + 0][i]; v.y = tile[d4 + 1][i];
            v.z = tile[d4 + 2][i]; v.w = tile[d4 + 3][i];
            *reinterpret_cast<uchar4*>(ob + (size_t)i * DH + d4) = v;
        }
    }
}

// ====== M partial = K^T V over a 128-position chunk (integers exact in f32) ======
// grid (BH=128, 8 chunks): full GPU. Staging via uint4 loads (1 instr replaces 16).
__global__ __launch_bounds__(256) void ktv_part_k(const uint8_t* __restrict__ Kb,
                                                  const uint8_t* __restrict__ Vb,
                                                  float* __restrict__ Mp)
{
    const int bh = blockIdx.x, ch = blockIdx.y;
    const uint8_t* kp = Kb + (size_t)bh * NLEN * DH;
    const uint8_t* vp = Vb + (size_t)bh * NLEN * DH;
    __shared__ float ks[64][68];
    __shared__ float vs[64][68];
    const int t = threadIdx.x;
    const int d2 = t & 63, g4 = t >> 6;
    const int r2 = t >> 2, dq = (t & 3) * 16;
    float acc[16];
#pragma unroll
    for (int j = 0; j < 16; ++j) acc[j] = 0.f;

    for (int nc = ch * 128; nc < ch * 128 + 128; nc += 64) {
        uint4 kv = *reinterpret_cast<const uint4*>(kp + (size_t)(nc + r2) * DH + dq);
        uint4 vv = *reinterpret_cast<const uint4*>(vp + (size_t)(nc + r2) * DH + dq);
        const uint8_t* k8 = reinterpret_cast<const uint8_t*>(&kv);
        const uint8_t* v8 = reinterpret_cast<const uint8_t*>(&vv);
#pragma unroll
        for (int j = 0; j < 16; j += 4) {
            float4 kf, vf;
            kf.x = (float)k8[j+0]; kf.y = (float)k8[j+1];
            kf.z = (float)k8[j+2]; kf.w = (float)k8[j+3];
            vf.x = (float)v8[j+0]; vf.y = (float)v8[j+1];
            vf.z = (float)v8[j+2]; vf.w = (float)v8[j+3];
            *reinterpret_cast<float4*>(&ks[r2][dq + j]) = kf;
            *reinterpret_cast<float4*>(&vs[r2][dq + j]) = vf;
        }
        __syncthreads();
        for (int n = 0; n < 64; ++n) {
            float vvv = vs[n][d2];
#pragma unroll
            for (int j = 0; j < 16; ++j)
                acc[j] += ks[n][g4 * 16 + j] * vvv;
        }
        __syncthreads();
    }
#pragma unroll
    for (int j = 0; j < 16; ++j)
        Mp[((size_t)ch * 128 + bh) * 4096 + (size_t)(g4 * 16 + j) * 64 + d2] = acc[j];
}

// ====== M = sum of 8 integer partials (exact in f32, order-free) ======
__global__ __launch_bounds__(256) void ktv_reduce_k(const float* __restrict__ Mp,
                                                    float* __restrict__ M)
{
    const int bh = blockIdx.x;
    const int t = threadIdx.x;
#pragma unroll
    for (int j = 0; j < 16; j += 4) {
        const int idx = t * 16 + j;
        float4 s = *reinterpret_cast<const float4*>(&Mp[(size_t)bh * 4096 + idx]);
#pragma unroll
        for (int c = 1; c < 8; ++c) {
            float4 v = *reinterpret_cast<const float4*>(&Mp[((size_t)c * 128 + bh) * 4096 + idx]);
            s.x += v.x; s.y += v.y; s.z += v.z; s.w += v.w;
        }
        *reinterpret_cast<float4*>(&M[(size_t)bh * 4096 + idx]) = s;
    }
}

// ================= attn = Q @ M, integer spike attn>=8, write [B,C,N] u8 =================
__global__ __launch_bounds__(256) void attn_spike_k(const uint8_t* __restrict__ Qb, const float* __restrict__ M,
                                                    uint8_t* __restrict__ A)
{
    const int nt = blockIdx.x, h = blockIdx.y, b = blockIdx.z;
    const int bh = b * NH + h;
    __shared__ float Ms[64][68];
    __shared__ float qs[64][65];
    const int t = threadIdx.x;
    const int r2 = t >> 2, cq = (t & 3) * 16;
    {
        // M: 4x float4 loads; Q: 1 uint4 load + transpose-write
        const float* mp = M + (size_t)bh * 4096 + (size_t)r2 * 64 + cq;
#pragma unroll
        for (int u = 0; u < 4; ++u)
            *reinterpret_cast<float4*>(&Ms[r2][cq + 4 * u]) =
                *reinterpret_cast<const float4*>(mp + 4 * u);
        uint4 qv = *reinterpret_cast<const uint4*>(
            Qb + ((size_t)bh * NLEN + nt * 64 + r2) * DH + cq);
        const uint8_t* q8 = reinterpret_cast<const uint8_t*>(&qv);
#pragma unroll
        for (int j = 0; j < 16; ++j)
            qs[cq + j][r2] = (float)q8[j];
    }
    __syncthreads();
    const int n = t & 63, dg = t >> 6;
    float acc[16];
#pragma unroll
    for (int j = 0; j < 16; ++j) acc[j] = 0.f;
    for (int d1 = 0; d1 < 64; ++d1) {
        float qv = qs[d1][n];
#pragma unroll
        for (int j = 0; j < 16; ++j)
            acc[j] += qv * Ms[d1][dg * 16 + j];
    }
#pragma unroll
    for (int j = 0; j < 16; ++j) {
        int d = dg * 16 + j;
        A[((size_t)b * CCH + h * 64 + d) * NLEN + nt * 64 + n] = (acc[j] >= 8.0f) ? 1 : 0;
    }
}

// ================= spike -> u8 store at channel offset =================
__global__ __launch_bounds__(256) void spike_store_k(
    const float* __restrict__ Y, const float2* __restrict__ st,
    const float* __restrict__ g, const float* __restrict__ bet,
    uint8_t* __restrict__ H, int Oc, int o_off, int Otot)
{
    size_t i4 = (size_t)blockIdx.x * 256 + threadIdx.x;
    size_t total = (size_t)BATCH * Oc * (NLEN / 4);
    if (i4 >= total) return;
    int n4 = (int)(i4 & 255);
    int o  = (int)((i4 >> 8) % Oc);
    int b  = (int)(i4 / ((size_t)256 * Oc));
    float4 y = reinterpret_cast<const float4*>(Y)[i4];
    float2 s = st[o];
    float gg = g[o], bb = bet[o];
    uchar4 r;
    r.x = spike_f32(y.x, s, gg, bb) ? 1 : 0;
    r.y = spike_f32(y.y, s, gg, bb) ? 1 : 0;
    r.z = spike_f32(y.z, s, gg, bb) ? 1 : 0;
    r.w = spike_f32(y.w, s, gg, bb) ? 1 : 0;
    *reinterpret_cast<uchar4*>(H + ((size_t)(b * Otot + o_off + o)) * NLEN + n4 * 4) = r;
}

// ================= out = (x + ares) + spike(bn(Y)) in np f32 order =================
__global__ __launch_bounds__(256) void final_k(
    const float* __restrict__ Y, const float2* __restrict__ st,
    const float* __restrict__ g, const float* __restrict__ bet,
    const float* __restrict__ x, const uint8_t* __restrict__ ares,
    float* __restrict__ Out)
{
    size_t i4 = (size_t)blockIdx.x * 256 + threadIdx.x;
    size_t total = (size_t)BATCH * CCH * (NLEN / 4);
    if (i4 >= total) return;
    int o = (int)((i4 >> 8) % CCH);
    float4 y  = reinterpret_cast<const float4*>(Y)[i4];
    float4 xv = reinterpret_cast<const float4*>(x)[i4];
    uchar4 av = reinterpret_cast<const uchar4*>(ares)[i4];
    float2 s = st[o];
    float gg = g[o], bb = bet[o];
    float4 r;
    {
        float x1;
        x1 = xv.x + (float)av.x; r.x = x1 + (spike_f32(y.x, s, gg, bb) ? 1.0f : 0.0f);
        x1 = xv.y + (float)av.y; r.y = x1 + (spike_f32(y.y, s, gg, bb) ? 1.0f : 0.0f);
        x1 = xv.z + (float)av.z; r.z = x1 + (spike_f32(y.z, s, gg, bb) ? 1.0f : 0.0f);
        x1 = xv.w + (float)av.w; r.w = x1 + (spike_f32(y.w, s, gg, bb) ? 1.0f : 0.0f);
    }
    reinterpret_cast<float4*>(Out)[i4] = r;
}

extern "C" void kernel_launch(void* const* d_in, const int* in_sizes, int n_in,
                              void* d_out, int out_size, void* d_ws, size_t ws_size,
                              hipStream_t stream)
{
    const float* x         = (const float*)d_in[0];
    const float* q_w       = (const float*)d_in[1];
    const float* q_g       = (const float*)d_in[2];
    const float* q_b       = (const float*)d_in[3];
    const float* k_w       = (const float*)d_in[4];
    const float* k_g       = (const float*)d_in[5];
    const float* k_b       = (const float*)d_in[6];
    const float* v_w       = (const float*)d_in[7];
    const float* v_g       = (const float*)d_in[8];
    const float* v_b       = (const float*)d_in[9];
    const float* proj_w    = (const float*)d_in[10];
    const float* proj_bias = (const float*)d_in[11];
    const float* proj_g    = (const float*)d_in[12];
    const float* proj_b    = (const float*)d_in[13];
    const float* fc1_w     = (const float*)d_in[14];
    const float* fc1_bias  = (const float*)d_in[15];
    const float* fc1_g     = (const float*)d_in[16];
    const float* fc1_b     = (const float*)d_in[17];
    const float* fc2_w     = (const float*)d_in[18];
    const float* fc2_bias  = (const float*)d_in[19];
    const float* fc2_g     = (const float*)d_in[20];
    const float* fc2_b     = (const float*)d_in[21];
    float* out = (float*)d_out;

    char* ws = (char*)d_ws;
    const size_t MiB = 1ull << 20;
    if (ws_size < 124 * MiB) return;

    // ---- layout (124 MiB), phase-checked lifetimes ----
    // Phase qkv : Yq 0-96 | qb 96-104 | kb 104-112 | vb 112-120 | stats 123+
    // Phase attn: Mpart 16-32 (Yq dead) | Mbuf 120-122 | ab 0-8
    // Phase proj: Wt 104-108, bits 108-112 (kb/vb dead) | Af 0-64 | ares 64-72
    // Phase fc1 : Af 0-64 | hb 72-104 (qb dead)
    // Phase fc2 : Wt 104-108, bits 108-112 | Af 0-64 | final reads ares 64-72
    float*    Yq    = (float*)(ws);                  // 96 MiB fused qkv out
    float*    Af    = (float*)(ws);                  // 64 MiB GEMM out (later phases)
    uint8_t*  ab    = (uint8_t*)(ws);                //  8 MiB attention spikes
    float*    Mpart = (float*)(ws + 16 * MiB);       // 16 MiB ktv partials (attn phase)
    uint8_t*  ares  = (uint8_t*)(ws + 64 * MiB);     //  8 MiB proj spikes, live to end
    uint8_t*  hb    = (uint8_t*)(ws + 72 * MiB);     // 32 MiB fc1 spikes (72..104)
    uint8_t*  qb    = (uint8_t*)(ws + 96 * MiB);     //  8 MiB [B,H,N,D]
    uint8_t*  kb    = (uint8_t*)(ws + 104 * MiB);    //  8 MiB
    uint8_t*  vb    = (uint8_t*)(ws + 112 * MiB);    //  8 MiB
    float*    Wt    = (float*)(ws + 104 * MiB);      //  4 MiB (sparse Wt; kb dead by proj)
    unsigned long long* bits = (unsigned long long*)(ws + 108 * MiB);  // 4 MiB
    float*    Mbuf  = (float*)(ws + 120 * MiB);      //  2 MiB (attn phase)
    float2*   stats = (float2*)(ws + 123 * MiB);     // 12 KiB (1536 ch max)

    dim3 thr256(256), thr128(128);

    // --- fused q|k|v dense GEMM: W selected per-block, no weight copies ---
    gemm_k<0><<<dim3(8, 12, 16), thr256, 0, stream>>>(q_w, k_w, v_w, x, nullptr, nullptr, Yq,
                                                      1536, 512, 1024);
    bn_stats_np_k<<<dim3(1536), thr128, 0, stream>>>(Yq, 1536, stats);
    spike_pack_qkv_k<<<dim3(16, 24, 16), thr256, 0, stream>>>(Yq, stats, q_g, k_g, v_g,
                                                              q_b, k_b, v_b, qb, kb, vb);

    // --- attention (exact integers; ktv split 8x for occupancy) ---
    ktv_part_k<<<dim3(128, 8), thr256, 0, stream>>>(kb, vb, Mpart);
    ktv_reduce_k<<<dim3(128), thr256, 0, stream>>>(Mpart, Mbuf);
    attn_spike_k<<<dim3(16, 8, 16), thr256, 0, stream>>>(qb, Mbuf, ab);

    // --- proj (sparse binary-input GEMM) ---
    wt_k<<<dim3(16, 16), thr256, 0, stream>>>(proj_w, Wt, 512, 512, 0, 512);
    col_bits_k<<<dim3(16, 8, 16), thr256, 0, stream>>>(ab, bits, 512);
    sparse_gemm_k<<<dim3(4096), thr256, 0, stream>>>(Wt, bits, proj_bias, Af, 512);
    bn_stats_np_k<<<dim3(512), thr128, 0, stream>>>(Af, 512, stats);
    spike_store_k<<<dim3(8192), thr256, 0, stream>>>(Af, stats, proj_g, proj_b, ares, 512, 0, 512);

    // --- fc1 on x1 = f32(x + ares), dense, 2 chunks of 1024 out-ch ---
    for (int ch = 0; ch < 2; ++ch) {
        const float* Wc = fc1_w + (size_t)ch * 1024 * 512;
        gemm_k<2><<<dim3(8, 8, 16), thr256, 0, stream>>>(Wc, Wc, Wc, x, ares,
                                                         fc1_bias + ch * 1024, Af,
                                                         1024, 512, 1024);
        bn_stats_np_k<<<dim3(1024), thr128, 0, stream>>>(Af, 1024, stats);
        spike_store_k<<<dim3(16384), thr256, 0, stream>>>(Af, stats, fc1_g + ch * 1024, fc1_b + ch * 1024,
                                                          hb, 1024, ch * 1024, 2048);
    }

    // --- fc2 (sparse binary-input GEMM) + final residual ---
    wt_k<<<dim3(64, 16), thr256, 0, stream>>>(fc2_w, Wt, 512, 2048, 0, 512);
    col_bits_k<<<dim3(16, 32, 16), thr256, 0, stream>>>(hb, bits, 2048);
    sparse_gemm_k<<<dim3(4096), thr256, 0, stream>>>(Wt, bits, fc2_bias, Af, 2048);
    bn_stats_np_k<<<dim3(512), thr128, 0, stream>>>(Af, 512, stats);
    final_k<<<dim3(8192), thr256, 0, stream>>>(Af, stats, fc2_g, fc2_b, x, ares, out);
}